// Round 8
// baseline (5364.393 us; speedup 1.0000x reference)
//
#include <hip/hip_runtime.h>
#include <stdint.h>

#define K_DIM 4096
#define N_DIM 11008
#define M_DIM 8192

constexpr int BM = 256, BN = 256, BK = 64;
constexpr int LDA = 72;            // f16 elems/row: 144 B stride (R2-proven)
constexpr int NT  = K_DIM / BK;    // 64
constexpr int NZW = N_DIM / 8;     // 1376
constexpr int NXT = N_DIM / BN;    // 43
constexpr int MXT = M_DIM / BM;    // 32
constexpr int NWG = NXT * MXT;     // 1376 = 8 * 172

typedef _Float16 f16x2 __attribute__((ext_vector_type(2)));
typedef _Float16 f16x8 __attribute__((ext_vector_type(8)));
typedef float    f32x4 __attribute__((ext_vector_type(4)));
union H8 { f16x8 v; f16x2 p[4]; };

// word w holds nibbles for k-offsets 0..7; output k-order (0,4,1,5,2,6,3,7).
// Exact: (1024+q) - (1024+z) is Sterbenz-exact; single rounding on *s.
__device__ __forceinline__ f16x8 dq_word(uint32_t w, f16x2 ss, f16x2 zz) {
    H8 r;
    uint32_t t0 = ( w        & 0x000F000Fu) | 0x64006400u;
    uint32_t t1 = ((w >> 4)  & 0x000F000Fu) | 0x64006400u;
    uint32_t t2 = ((w >> 8)  & 0x000F000Fu) | 0x64006400u;
    uint32_t t3 = ((w >> 12) & 0x000F000Fu) | 0x64006400u;
    r.p[0] = (__builtin_bit_cast(f16x2, t0) - zz) * ss;
    r.p[1] = (__builtin_bit_cast(f16x2, t1) - zz) * ss;
    r.p[2] = (__builtin_bit_cast(f16x2, t2) - zz) * ss;
    r.p[3] = (__builtin_bit_cast(f16x2, t3) - zz) * ss;
    return r.v;
}

// No-drain barrier (R7-proven): lgkmcnt(0) for cross-wave LDS visibility,
// raw s_barrier, sched_barrier fence (rule #18). Global loads stay in flight.
#define BAR() do {                                           \
    asm volatile("s_waitcnt lgkmcnt(0)" ::: "memory");       \
    __builtin_amdgcn_s_barrier();                            \
    __builtin_amdgcn_sched_barrier(0);                       \
} while (0)

// ===== 256x256 tile, 8 waves (2M x 4N), wave-tile 128x64, A-in-LDS dbuf =====
__global__ __launch_bounds__(512, 2)
void qgemm_kernel(const float* __restrict__ x, const uint32_t* __restrict__ qw,
                  const uint32_t* __restrict__ qz, const float* __restrict__ sc,
                  const float* __restrict__ bias, float* __restrict__ out)
{
    __shared__ _Float16 As[2][BM * LDA];   // 2 x 36 KiB

    const int tid  = threadIdx.x;
    const int lid  = (blockIdx.x & 7) * (NWG / 8) + (blockIdx.x >> 3); // XCD swizzle
    const int m0   = (lid / NXT) * BM;
    const int n0   = (lid % NXT) * BN;

    const int lane = tid & 63, wid = tid >> 6;   // wid 0..7
    const int wr = wid >> 2;          // 0..1  (M position, 128 rows each)
    const int wc = wid & 3;           // 0..3  (N position, 64 cols each)
    const int lr = lane & 15, lk = lane >> 4;

    const int arow = tid >> 3;        // A staging row (0..63, +i*64)
    const int acp  = tid & 7;         // A staging col-octet

    f32x4 acc[8][4];
#pragma unroll
    for (int i = 0; i < 8; ++i)
#pragma unroll
        for (int j = 0; j < 4; ++j) {
            f32x4 z = {0.f, 0.f, 0.f, 0.f};
            acc[i][j] = z;
        }

    f32x4    aS[4][2];                // single staging reg-set (32 VGPR)
    uint32_t breg[2][8];              // two B sets (even/odd tiles)
    f16x2    ssv[4], zzv[4];
    float    s_nxt[4];
    uint32_t z_nxt[4];

    const int   ncb = n0 + wc * 64 + lr;
    const int   shz = 4 * (lr & 7);
    const float* xbase = x + (size_t)(m0 + arow) * K_DIM + acp * 8;

    const uint32_t* qp0 = qw + (size_t)lk * N_DIM + ncb;
    const uint32_t* qp1 = qp0 + (size_t)4 * N_DIM;

#define A_LOAD(KT) do { const float* ap_ = xbase + (KT) * BK;                \
    _Pragma("unroll") for (int i = 0; i < 4; ++i) {                          \
        const float* src_ = ap_ + (size_t)(i * 64) * K_DIM;                  \
        aS[i][0] = *(const f32x4*)(src_);                                    \
        aS[i][1] = *(const f32x4*)(src_ + 4); } } while (0)

#define A_WRITE(BUF) do {                                                    \
    _Pragma("unroll") for (int i = 0; i < 4; ++i) { H8 v_;                   \
        _Pragma("unroll") for (int j = 0; j < 4; ++j)                        \
            v_.p[j] = __builtin_bit_cast(f16x2,                              \
                __builtin_amdgcn_cvt_pkrtz(aS[i][0][j], aS[i][1][j]));       \
        *(f16x8*)&As[BUF][(arow + i * 64) * LDA + acp * 8] = v_.v; } } while (0)

#define LOADB(SET) do {                                                      \
    _Pragma("unroll") for (int j = 0; j < 4; ++j) breg[SET][j]     = qp0[j * 16]; \
    _Pragma("unroll") for (int j = 0; j < 4; ++j) breg[SET][4 + j] = qp1[j * 16]; \
    qp0 += (size_t)8 * N_DIM; qp1 += (size_t)8 * N_DIM; } while (0)

#define LOADSZ(g) do { _Pragma("unroll") for (int j = 0; j < 4; ++j) {       \
    s_nxt[j] = sc[(size_t)(g) * N_DIM + ncb + j * 16];                       \
    z_nxt[j] = qz[(size_t)(g) * NZW + (ncb >> 3) + j * 2]; } } while (0)

#define MAKESZ() do { _Pragma("unroll") for (int j = 0; j < 4; ++j) {        \
    _Float16 zh = (_Float16)(float)(1024u + ((z_nxt[j] >> shz) & 15u));      \
    _Float16 sh = (_Float16)s_nxt[j];                                        \
    f16x2 sp = {sh, sh}; ssv[j] = sp;                                        \
    f16x2 zp = {zh, zh}; zzv[j] = zp; } } while (0)

#define COMPUTE(BUF, SET) do {                                               \
    _Pragma("unroll") for (int ks = 0; ks < 2; ++ks) {                       \
        f16x8 bf[4];                                                         \
        _Pragma("unroll") for (int j = 0; j < 4; ++j)                        \
            bf[j] = dq_word(breg[SET][ks * 4 + j], ssv[j], zzv[j]);          \
        _Pragma("unroll") for (int i = 0; i < 8; ++i) {                      \
            f16x8 af_ = *(const f16x8*)&As[BUF][(wr * 128 + i * 16 + lr) * LDA + ks * 32 + lk * 8]; \
            _Pragma("unroll") for (int j = 0; j < 4; ++j)                    \
                acc[i][j] = __builtin_amdgcn_mfma_f32_16x16x32_f16(af_, bf[j], acc[i][j], 0, 0, 0); \
        } } } while (0)

    // ---------------- prologue ----------------
    LOADSZ(0);          // raw s/z for group 0
    A_LOAD(0);          // tile 0
    LOADB(0);           // tile 0 -> set 0
    MAKESZ();           // group 0
    A_WRITE(0);         // tile 0 -> buf0 (prologue-only vmcnt wait)
    BAR();

    for (int kt2 = 0; kt2 < NT / 2; ++kt2) {
        const int t0 = 2 * kt2;
        // ---- even tile t0 (buf0, set0); stage tile t0+1 -> buf1 ----
        A_LOAD(t0 + 1);         // issue early, lands during COMPUTE
        LOADB(1);               // tile t0+1 B words, in flight during COMPUTE
        COMPUTE(0, 0);
        A_WRITE(1);             // vmcnt wait hidden behind COMPUTE
        BAR();

        // ---- odd tile t0+1 (buf1, set1); stage tile t0+2 -> buf0 ----
        if (kt2 + 1 < NT / 2) {
            A_LOAD(t0 + 2);
            LOADB(0);
            LOADSZ(kt2 + 1);    // next group's raw s/z
            COMPUTE(1, 1);
            A_WRITE(0);
            MAKESZ();           // group kt2+1 (after COMPUTE consumed old ssv/zzv)
        } else {
            COMPUTE(1, 1);
        }
        BAR();
    }

#undef A_LOAD
#undef A_WRITE
#undef LOADB
#undef LOADSZ
#undef MAKESZ
#undef COMPUTE

    // epilogue: C/D layout col = lane&15, row = (lane>>4)*4 + reg
    const int ccol0 = n0 + wc * 64 + lr;
    float bj[4];
#pragma unroll
    for (int j = 0; j < 4; ++j) bj[j] = bias[ccol0 + j * 16];
#pragma unroll
    for (int i = 0; i < 8; ++i) {
        const int rbase = m0 + wr * 128 + i * 16 + lk * 4;
#pragma unroll
        for (int j = 0; j < 4; ++j) {
            const int col = ccol0 + j * 16;
#pragma unroll
            for (int r = 0; r < 4; ++r)
                out[(size_t)(rbase + r) * N_DIM + col] = acc[i][j][r] + bj[j];
        }
    }
}

extern "C" void kernel_launch(void* const* d_in, const int* in_sizes, int n_in,
                              void* d_out, int out_size, void* d_ws, size_t ws_size,
                              hipStream_t stream) {
    const float*    xp = (const float*)d_in[0];
    const uint32_t* qw = (const uint32_t*)d_in[1];
    const uint32_t* qz = (const uint32_t*)d_in[2];
    const float*    sc = (const float*)d_in[3];
    const float*    bi = (const float*)d_in[4];
    float*          op = (float*)d_out;
    (void)in_sizes; (void)n_in; (void)d_ws; (void)ws_size; (void)out_size;

    qgemm_kernel<<<dim3(NWG), dim3(512), 0, stream>>>(xp, qw, qz, sc, bi, op);
}

// Round 9
// 4238.588 us; speedup vs baseline: 1.2656x; 1.2656x over previous
//
#include <hip/hip_runtime.h>
#include <stdint.h>

#define K_DIM 4096
#define N_DIM 11008
#define M_DIM 8192

constexpr int BM = 256, BN = 256, BK = 64;
constexpr int NT  = K_DIM / BK;      // 64
constexpr int NZW = N_DIM / 8;       // 1376
constexpr int NXT = N_DIM / BN;      // 43
constexpr int MXT = M_DIM / BM;      // 32
constexpr int NWG = NXT * MXT;       // 1376 = 8 * 172
constexpr int TILE_ELEMS = BM * BK;  // 16384 f16 = 32 KiB per K-tile

typedef _Float16 f16x2 __attribute__((ext_vector_type(2)));
typedef _Float16 f16x8 __attribute__((ext_vector_type(8)));
typedef float    f32x4 __attribute__((ext_vector_type(4)));
union H8 { f16x8 v; f16x2 p[4]; };

// word w holds nibbles for k-offsets 0..7; output k-order (0,4,1,5,2,6,3,7).
// Exact: (1024+q) - (1024+z) is Sterbenz-exact; single rounding on *s.
__device__ __forceinline__ f16x8 dq_word(uint32_t w, f16x2 ss, f16x2 zz) {
    H8 r;
    uint32_t t0 = ( w        & 0x000F000Fu) | 0x64006400u;
    uint32_t t1 = ((w >> 4)  & 0x000F000Fu) | 0x64006400u;
    uint32_t t2 = ((w >> 8)  & 0x000F000Fu) | 0x64006400u;
    uint32_t t3 = ((w >> 12) & 0x000F000Fu) | 0x64006400u;
    r.p[0] = (__builtin_bit_cast(f16x2, t0) - zz) * ss;
    r.p[1] = (__builtin_bit_cast(f16x2, t1) - zz) * ss;
    r.p[2] = (__builtin_bit_cast(f16x2, t2) - zz) * ss;
    r.p[3] = (__builtin_bit_cast(f16x2, t3) - zz) * ss;
    return r.v;
}

// ========= pre-pass: x fp32 -> f16, fragment-major 256-row tiles =========
// x16 layout: [mt(32)][kt(64)][fk(8)][row(256)][octet(8)], octet holds pairs
// (e, e+4) of k = kt*64 + fk*8 + e  (matches dq_word's output permutation).
__global__ __launch_bounds__(512)
void prep_kernel(const float* __restrict__ x, _Float16* __restrict__ x16) {
    const int b  = blockIdx.x;          // mt*64 + kt
    const int mt = b >> 6, kt = b & 63;
    _Float16* dst = x16 + (size_t)b * TILE_ELEMS;
#pragma unroll
    for (int it = 0; it < 4; ++it) {
        const int o   = it * 512 + threadIdx.x;   // 0..2047 = fk*256 + row
        const int fk  = o >> 8, row = o & 255;
        const float* src = x + (size_t)(mt * 256 + row) * K_DIM + kt * 64 + fk * 8;
        f32x4 a0 = *(const f32x4*)src;
        f32x4 a1 = *(const f32x4*)(src + 4);
        H8 v;
#pragma unroll
        for (int j = 0; j < 4; ++j)
            v.p[j] = __builtin_bit_cast(f16x2, __builtin_amdgcn_cvt_pkrtz(a0[j], a1[j]));
        *(f16x8*)(dst + (size_t)o * 8) = v.v;
    }
}

// ===== 256x256, 8 waves (2M x 4N), wave-tile 128x64; A via global_load_lds dbuf =====
__global__ __launch_bounds__(512, 2)
void qgemm256_kernel(const _Float16* __restrict__ x16, const uint32_t* __restrict__ qw,
                     const uint32_t* __restrict__ qz, const float* __restrict__ sc,
                     const float* __restrict__ bias, float* __restrict__ out)
{
    __shared__ _Float16 As[2 * TILE_ELEMS];   // 2 x 32 KiB, fragment-major, linear

    const int tid  = threadIdx.x;
    const int lid  = (blockIdx.x & 7) * (NWG / 8) + (blockIdx.x >> 3); // XCD swizzle
    const int mt   = lid / NXT;
    const int n0   = (lid % NXT) * BN;

    const int lane = tid & 63, wid = tid >> 6;   // wid 0..7
    const int wr = wid >> 2;          // 0..1  (M, 128 rows)
    const int wc = wid & 3;           // 0..3  (N, 64 cols)
    const int lr = lane & 15, lk = lane >> 4;

    f32x4 acc[8][4];
#pragma unroll
    for (int i = 0; i < 8; ++i)
#pragma unroll
        for (int j = 0; j < 4; ++j) {
            f32x4 z = {0.f, 0.f, 0.f, 0.f};
            acc[i][j] = z;
        }

    uint32_t breg[2][8];
    f16x2    ssv[4], zzv[4];
    float    s_nxt[4];
    uint32_t z_nxt[4];

    const int ncb = n0 + wc * 64 + lr;
    const int shz = 4 * (lr & 7);

    const _Float16* xsrc = x16 + (size_t)mt * (64 * TILE_ELEMS) + tid * 8;
    const uint32_t* qp0 = qw + (size_t)lk * N_DIM + ncb;
    const uint32_t* qp1 = qp0 + (size_t)4 * N_DIM;

#define STAGE(BUF, KT) do {                                                  \
    const _Float16* s_ = xsrc + (size_t)(KT) * TILE_ELEMS;                   \
    _Float16* d_ = &As[(BUF) * TILE_ELEMS + tid * 8];                        \
    _Pragma("unroll") for (int it = 0; it < 4; ++it)                         \
        __builtin_amdgcn_global_load_lds(                                    \
            (const __attribute__((address_space(1))) void*)(s_ + it * 4096), \
            (__attribute__((address_space(3))) void*)(d_ + it * 4096), 16, 0, 0); \
    } while (0)

#define LOADB(SET) do {                                                      \
    _Pragma("unroll") for (int j = 0; j < 4; ++j) breg[SET][j]     = qp0[j * 16]; \
    _Pragma("unroll") for (int j = 0; j < 4; ++j) breg[SET][4 + j] = qp1[j * 16]; \
    qp0 += (size_t)8 * N_DIM; qp1 += (size_t)8 * N_DIM; } while (0)

#define LOADSZ(g) do { _Pragma("unroll") for (int j = 0; j < 4; ++j) {       \
    s_nxt[j] = sc[(size_t)(g) * N_DIM + ncb + j * 16];                       \
    z_nxt[j] = qz[(size_t)(g) * NZW + (ncb >> 3) + j * 2]; } } while (0)

#define MAKESZ() do { _Pragma("unroll") for (int j = 0; j < 4; ++j) {        \
    _Float16 zh = (_Float16)(float)(1024u + ((z_nxt[j] >> shz) & 15u));      \
    _Float16 sh = (_Float16)s_nxt[j];                                        \
    f16x2 sp = {sh, sh}; ssv[j] = sp;                                        \
    f16x2 zp = {zh, zh}; zzv[j] = zp; } } while (0)

#define COMPUTE(BUF, SET) do {                                               \
    _Pragma("unroll") for (int ks = 0; ks < 2; ++ks) {                       \
        f16x8 bf[4];                                                         \
        _Pragma("unroll") for (int j = 0; j < 4; ++j)                        \
            bf[j] = dq_word(breg[SET][ks * 4 + j], ssv[j], zzv[j]);          \
        _Pragma("unroll") for (int i = 0; i < 8; ++i) {                      \
            f16x8 af_ = *(const f16x8*)&As[(BUF) * TILE_ELEMS                \
                + (ks * 4 + lk) * 2048 + (wr * 128 + i * 16 + lr) * 8];      \
            _Pragma("unroll") for (int j = 0; j < 4; ++j)                    \
                acc[i][j] = __builtin_amdgcn_mfma_f32_16x16x32_f16(af_, bf[j], acc[i][j], 0, 0, 0); \
        } } } while (0)

    // ---------------- prologue ----------------
    LOADSZ(0);
    STAGE(0, 0);
    LOADB(0);
    MAKESZ();
    __syncthreads();    // vmcnt(0) drain: tile-0 DMA complete

    for (int kt2 = 0; kt2 < NT / 2; ++kt2) {
        const int t0 = 2 * kt2;
        // ---- even tile t0 (buf0, set0); stage t0+1 -> buf1 ----
        STAGE(1, t0 + 1);       // DMA issued, lands during COMPUTE
        LOADB(1);               // B(t0+1) in flight during COMPUTE
        COMPUTE(0, 0);
        __syncthreads();        // drain = cheap (loads issued a full COMPUTE ago)

        // ---- odd tile t0+1 (buf1, set1); stage t0+2 -> buf0 ----
        if (kt2 + 1 < NT / 2) {
            STAGE(0, t0 + 2);
            LOADB(0);
            LOADSZ(kt2 + 1);    // next group's raw s/z
            COMPUTE(1, 1);      // uses group kt2's ssv/zzv
            MAKESZ();           // group kt2+1 (after COMPUTE consumed old ssv/zzv)
        } else {
            COMPUTE(1, 1);
        }
        __syncthreads();
    }

#undef STAGE
#undef LOADB
#undef LOADSZ
#undef MAKESZ
#undef COMPUTE

    // epilogue: C/D layout col = lane&15, row = (lane>>4)*4 + reg
    const int ccol0 = n0 + wc * 64 + lr;
    float bj[4];
#pragma unroll
    for (int j = 0; j < 4; ++j) bj[j] = bias[ccol0 + j * 16];
    const int m0 = mt * BM;
#pragma unroll
    for (int i = 0; i < 8; ++i) {
        const int rbase = m0 + wr * 128 + i * 16 + lk * 4;
#pragma unroll
        for (int j = 0; j < 4; ++j) {
            const int col = ccol0 + j * 16;
#pragma unroll
            for (int r = 0; r < 4; ++r)
                out[(size_t)(rbase + r) * N_DIM + col] = acc[i][j][r] + bj[j];
        }
    }
}

// ================= fallback (R7 kernel, 958 µs proven) for small ws =================
constexpr int FB_BM = 128, FB_BN = 128;
constexpr int FB_NXT = N_DIM / FB_BN;   // 86
constexpr int FB_NWG = FB_NXT * (M_DIM / FB_BM); // 5504

#define BAR() do {                                           \
    asm volatile("s_waitcnt lgkmcnt(0)" ::: "memory");       \
    __builtin_amdgcn_s_barrier();                            \
    __builtin_amdgcn_sched_barrier(0);                       \
} while (0)

__global__ __launch_bounds__(256, 3)
void qgemm_fb_kernel(const float* __restrict__ x, const uint32_t* __restrict__ qw,
                     const uint32_t* __restrict__ qz, const float* __restrict__ sc,
                     const float* __restrict__ bias, float* __restrict__ out)
{
    constexpr int LDA = 72;
    __shared__ _Float16 As[2][FB_BM * LDA];

    const int tid  = threadIdx.x;
    const int lid  = (blockIdx.x & 7) * (FB_NWG / 8) + (blockIdx.x >> 3);
    const int m0   = (lid / FB_NXT) * FB_BM;
    const int n0   = (lid % FB_NXT) * FB_BN;
    const int lane = tid & 63, wid = tid >> 6;
    const int wr = wid >> 1, wc = wid & 1;
    const int lr = lane & 15, lk = lane >> 4;
    const int arow = tid >> 3, acp = tid & 7;

    f32x4 acc[4][4];
#pragma unroll
    for (int i = 0; i < 4; ++i)
#pragma unroll
        for (int j = 0; j < 4; ++j) { f32x4 z = {0.f,0.f,0.f,0.f}; acc[i][j] = z; }

    f32x4    aE[4][2], aO[4][2];
    uint32_t breg[8], bregN[8];
    f16x2    ssv[4], zzv[4];
    float    s_nxt[4];
    uint32_t z_nxt[4];

    const int   ncb = n0 + wc * 64 + lr;
    const int   shz = 4 * (lr & 7);
    const float* xbase = x + (size_t)(m0 + arow) * K_DIM + acp * 8;
    const uint32_t* qp0 = qw + (size_t)lk * N_DIM + ncb;
    const uint32_t* qp1 = qp0 + (size_t)4 * N_DIM;

#define A_LOAD(S, KT) do { const float* ap_ = xbase + (KT) * BK;             \
    _Pragma("unroll") for (int i = 0; i < 4; ++i) {                          \
        const float* src_ = ap_ + (size_t)(i * 32) * K_DIM;                  \
        S[i][0] = *(const f32x4*)(src_);                                     \
        S[i][1] = *(const f32x4*)(src_ + 4); } } while (0)

#define A_WRITE(S, BUF) do {                                                 \
    _Pragma("unroll") for (int i = 0; i < 4; ++i) { H8 v_;                   \
        _Pragma("unroll") for (int j = 0; j < 4; ++j)                        \
            v_.p[j] = __builtin_bit_cast(f16x2,                              \
                __builtin_amdgcn_cvt_pkrtz(S[i][0][j], S[i][1][j]));         \
        *(f16x8*)&As[BUF][(arow + i * 32) * LDA + acp * 8] = v_.v; } } while (0)

#define LOADB() do {                                                         \
    _Pragma("unroll") for (int j = 0; j < 4; ++j) bregN[j]     = qp0[j * 16]; \
    _Pragma("unroll") for (int j = 0; j < 4; ++j) bregN[4 + j] = qp1[j * 16]; \
    qp0 += (size_t)8 * N_DIM; qp1 += (size_t)8 * N_DIM; } while (0)

#define COPYB() do { _Pragma("unroll") for (int q = 0; q < 8; ++q) breg[q] = bregN[q]; } while (0)

#define LOADSZ(g) do { _Pragma("unroll") for (int j = 0; j < 4; ++j) {       \
    s_nxt[j] = sc[(size_t)(g) * N_DIM + ncb + j * 16];                       \
    z_nxt[j] = qz[(size_t)(g) * NZW + (ncb >> 3) + j * 2]; } } while (0)

#define MAKESZ() do { _Pragma("unroll") for (int j = 0; j < 4; ++j) {        \
    _Float16 zh = (_Float16)(float)(1024u + ((z_nxt[j] >> shz) & 15u));      \
    _Float16 sh = (_Float16)s_nxt[j];                                        \
    f16x2 sp = {sh, sh}; ssv[j] = sp;                                        \
    f16x2 zp = {zh, zh}; zzv[j] = zp; } } while (0)

#define COMPUTE(BUF) do {                                                    \
    _Pragma("unroll") for (int ks = 0; ks < 2; ++ks) {                       \
        f16x8 af[4], bf[4];                                                  \
        _Pragma("unroll") for (int i = 0; i < 4; ++i)                        \
            af[i] = *(const f16x8*)&As[BUF][(wr * 64 + i * 16 + lr) * LDA + ks * 32 + lk * 8]; \
        _Pragma("unroll") for (int j = 0; j < 4; ++j)                        \
            bf[j] = dq_word(breg[ks * 4 + j], ssv[j], zzv[j]);               \
        _Pragma("unroll") for (int i = 0; i < 4; ++i)                        \
            _Pragma("unroll") for (int j = 0; j < 4; ++j)                    \
                acc[i][j] = __builtin_amdgcn_mfma_f32_16x16x32_f16(af[i], bf[j], acc[i][j], 0, 0, 0); \
    } } while (0)

    LOADSZ(0);
    A_LOAD(aE, 0);
    LOADB();
    A_WRITE(aE, 0);
    A_LOAD(aO, 1);
    BAR();

    for (int kt2 = 0; kt2 < NT / 2; ++kt2) {
        const int t0 = 2 * kt2;
        MAKESZ();
        COPYB();
        LOADB();
        A_WRITE(aO, 1);
        if (kt2 + 1 < NT / 2) A_LOAD(aE, t0 + 2);
        COMPUTE(0);
        BAR();

        COPYB();
        if (kt2 + 1 < NT / 2) {
            LOADB();
            LOADSZ(kt2 + 1);
            A_WRITE(aE, 0);
            A_LOAD(aO, t0 + 3);
        }
        COMPUTE(1);
        BAR();
    }

#undef A_LOAD
#undef A_WRITE
#undef LOADB
#undef COPYB
#undef LOADSZ
#undef MAKESZ
#undef COMPUTE

    const int ccol0 = n0 + wc * 64 + lr;
    float bj[4];
#pragma unroll
    for (int j = 0; j < 4; ++j) bj[j] = bias[ccol0 + j * 16];
#pragma unroll
    for (int i = 0; i < 4; ++i) {
        const int rbase = m0 + wr * 64 + i * 16 + lk * 4;
#pragma unroll
        for (int j = 0; j < 4; ++j) {
            const int col = ccol0 + j * 16;
#pragma unroll
            for (int r = 0; r < 4; ++r)
                out[(size_t)(rbase + r) * N_DIM + col] = acc[i][j][r] + bj[j];
        }
    }
}

extern "C" void kernel_launch(void* const* d_in, const int* in_sizes, int n_in,
                              void* d_out, int out_size, void* d_ws, size_t ws_size,
                              hipStream_t stream) {
    const float*    xp = (const float*)d_in[0];
    const uint32_t* qw = (const uint32_t*)d_in[1];
    const uint32_t* qz = (const uint32_t*)d_in[2];
    const float*    sc = (const float*)d_in[3];
    const float*    bi = (const float*)d_in[4];
    float*          op = (float*)d_out;
    (void)in_sizes; (void)n_in; (void)out_size;

    const size_t need = (size_t)M_DIM * K_DIM * sizeof(_Float16); // 64 MiB
    if (ws_size >= need) {
        prep_kernel<<<dim3(MXT * NT), dim3(512), 0, stream>>>(xp, (_Float16*)d_ws);
        qgemm256_kernel<<<dim3(NWG), dim3(512), 0, stream>>>((const _Float16*)d_ws, qw, qz, sc, bi, op);
    } else {
        qgemm_fb_kernel<<<dim3(FB_NWG), dim3(256), 0, stream>>>(xp, qw, qz, sc, bi, op);
    }
}

// Round 10
// 4147.496 us; speedup vs baseline: 1.2934x; 1.0220x over previous
//
#include <hip/hip_runtime.h>
#include <stdint.h>

#define K_DIM 4096
#define N_DIM 11008
#define M_DIM 8192

constexpr int BM = 256, BN = 256, BK = 64;
constexpr int NT  = K_DIM / BK;      // 64
constexpr int NZW = N_DIM / 8;       // 1376
constexpr int NXT = N_DIM / BN;      // 43
constexpr int MXT = M_DIM / BM;      // 32
constexpr int NWG = NXT * MXT;       // 1376 = 8 * 172
constexpr int TILE_ELEMS = BM * BK;  // 16384 f16 = 32 KiB per K-tile

typedef _Float16 f16x2 __attribute__((ext_vector_type(2)));
typedef _Float16 f16x8 __attribute__((ext_vector_type(8)));
typedef float    f32x4 __attribute__((ext_vector_type(4)));
union H8 { f16x8 v; f16x2 p[4]; };

// word w holds nibbles for k-offsets 0..7; output k-order (0,4,1,5,2,6,3,7).
// Exact: (1024+q) - (1024+z) is Sterbenz-exact; single rounding on *s.
__device__ __forceinline__ f16x8 dq_word(uint32_t w, f16x2 ss, f16x2 zz) {
    H8 r;
    uint32_t t0 = ( w        & 0x000F000Fu) | 0x64006400u;
    uint32_t t1 = ((w >> 4)  & 0x000F000Fu) | 0x64006400u;
    uint32_t t2 = ((w >> 8)  & 0x000F000Fu) | 0x64006400u;
    uint32_t t3 = ((w >> 12) & 0x000F000Fu) | 0x64006400u;
    r.p[0] = (__builtin_bit_cast(f16x2, t0) - zz) * ss;
    r.p[1] = (__builtin_bit_cast(f16x2, t1) - zz) * ss;
    r.p[2] = (__builtin_bit_cast(f16x2, t2) - zz) * ss;
    r.p[3] = (__builtin_bit_cast(f16x2, t3) - zz) * ss;
    return r.v;
}

// ========= pre-pass: x fp32 -> f16, fragment-major 256-row tiles =========
// x16 layout: [mt(32)][kt(64)][fk(8)][row(256)][octet(8)], octet holds pairs
// (e, e+4) of k = kt*64 + fk*8 + e  (matches dq_word's output permutation).
__global__ __launch_bounds__(512)
void prep_kernel(const float* __restrict__ x, _Float16* __restrict__ x16) {
    const int b  = blockIdx.x;          // mt*64 + kt
    const int mt = b >> 6, kt = b & 63;
    _Float16* dst = x16 + (size_t)b * TILE_ELEMS;
#pragma unroll
    for (int it = 0; it < 4; ++it) {
        const int o   = it * 512 + threadIdx.x;   // 0..2047 = fk*256 + row
        const int fk  = o >> 8, row = o & 255;
        const float* src = x + (size_t)(mt * 256 + row) * K_DIM + kt * 64 + fk * 8;
        f32x4 a0 = *(const f32x4*)src;
        f32x4 a1 = *(const f32x4*)(src + 4);
        H8 v;
#pragma unroll
        for (int j = 0; j < 4; ++j)
            v.p[j] = __builtin_bit_cast(f16x2, __builtin_amdgcn_cvt_pkrtz(a0[j], a1[j]));
        *(f16x8*)(dst + (size_t)o * 8) = v.v;
    }
}

// ===== 256x256, 8 waves (2M x 4N), wave-tile 128x64; A via global_load_lds dbuf =====
// __launch_bounds__(512, 1): register budget 512/wave (unified VGPR+AGPR).
// R9's (512,2) capped the budget at 256 = acc(128) + working set -> per-tile
// spill (10.5 GB scratch writes). Occupancy is 1 block/CU either way (LDS+VGPR),
// so declaring 1 wave/EU costs nothing and removes the spill.
__global__ __launch_bounds__(512, 1)
void qgemm256_kernel(const _Float16* __restrict__ x16, const uint32_t* __restrict__ qw,
                     const uint32_t* __restrict__ qz, const float* __restrict__ sc,
                     const float* __restrict__ bias, float* __restrict__ out)
{
    __shared__ _Float16 As[2 * TILE_ELEMS];   // 2 x 32 KiB, fragment-major, linear

    const int tid  = threadIdx.x;
    const int lid  = (blockIdx.x & 7) * (NWG / 8) + (blockIdx.x >> 3); // XCD swizzle
    const int mt   = lid / NXT;
    const int n0   = (lid % NXT) * BN;

    const int lane = tid & 63, wid = tid >> 6;   // wid 0..7
    const int wr = wid >> 2;          // 0..1  (M, 128 rows)
    const int wc = wid & 3;           // 0..3  (N, 64 cols)
    const int lr = lane & 15, lk = lane >> 4;

    f32x4 acc[8][4];
#pragma unroll
    for (int i = 0; i < 8; ++i)
#pragma unroll
        for (int j = 0; j < 4; ++j) {
            f32x4 z = {0.f, 0.f, 0.f, 0.f};
            acc[i][j] = z;
        }

    uint32_t breg[2][8];
    f16x2    ssv[4], zzv[4];
    float    s_nxt[4];
    uint32_t z_nxt[4];

    const int ncb = n0 + wc * 64 + lr;
    const int shz = 4 * (lr & 7);

    const _Float16* xsrc = x16 + (size_t)mt * (64 * TILE_ELEMS) + tid * 8;
    const uint32_t* qp0 = qw + (size_t)lk * N_DIM + ncb;
    const uint32_t* qp1 = qp0 + (size_t)4 * N_DIM;

#define STAGE(BUF, KT) do {                                                  \
    const _Float16* s_ = xsrc + (size_t)(KT) * TILE_ELEMS;                   \
    _Float16* d_ = &As[(BUF) * TILE_ELEMS + tid * 8];                        \
    _Pragma("unroll") for (int it = 0; it < 4; ++it)                         \
        __builtin_amdgcn_global_load_lds(                                    \
            (const __attribute__((address_space(1))) void*)(s_ + it * 4096), \
            (__attribute__((address_space(3))) void*)(d_ + it * 4096), 16, 0, 0); \
    } while (0)

#define LOADB(SET) do {                                                      \
    _Pragma("unroll") for (int j = 0; j < 4; ++j) breg[SET][j]     = qp0[j * 16]; \
    _Pragma("unroll") for (int j = 0; j < 4; ++j) breg[SET][4 + j] = qp1[j * 16]; \
    qp0 += (size_t)8 * N_DIM; qp1 += (size_t)8 * N_DIM; } while (0)

#define LOADSZ(g) do { _Pragma("unroll") for (int j = 0; j < 4; ++j) {       \
    s_nxt[j] = sc[(size_t)(g) * N_DIM + ncb + j * 16];                       \
    z_nxt[j] = qz[(size_t)(g) * NZW + (ncb >> 3) + j * 2]; } } while (0)

#define MAKESZ() do { _Pragma("unroll") for (int j = 0; j < 4; ++j) {        \
    _Float16 zh = (_Float16)(float)(1024u + ((z_nxt[j] >> shz) & 15u));      \
    _Float16 sh = (_Float16)s_nxt[j];                                        \
    f16x2 sp = {sh, sh}; ssv[j] = sp;                                        \
    f16x2 zp = {zh, zh}; zzv[j] = zp; } } while (0)

#define COMPUTE(BUF, SET) do {                                               \
    _Pragma("unroll") for (int ks = 0; ks < 2; ++ks) {                       \
        f16x8 bf[4];                                                         \
        _Pragma("unroll") for (int j = 0; j < 4; ++j)                        \
            bf[j] = dq_word(breg[SET][ks * 4 + j], ssv[j], zzv[j]);          \
        _Pragma("unroll") for (int i = 0; i < 8; ++i) {                      \
            f16x8 af_ = *(const f16x8*)&As[(BUF) * TILE_ELEMS                \
                + (ks * 4 + lk) * 2048 + (wr * 128 + i * 16 + lr) * 8];      \
            _Pragma("unroll") for (int j = 0; j < 4; ++j)                    \
                acc[i][j] = __builtin_amdgcn_mfma_f32_16x16x32_f16(af_, bf[j], acc[i][j], 0, 0, 0); \
        } } } while (0)

    // ---------------- prologue ----------------
    LOADSZ(0);
    STAGE(0, 0);
    LOADB(0);
    MAKESZ();
    __syncthreads();    // vmcnt(0) drain: tile-0 DMA complete

    for (int kt2 = 0; kt2 < NT / 2; ++kt2) {
        const int t0 = 2 * kt2;
        // ---- even tile t0 (buf0, set0); stage t0+1 -> buf1 ----
        STAGE(1, t0 + 1);       // DMA issued, lands during COMPUTE
        LOADB(1);               // B(t0+1) in flight during COMPUTE
        COMPUTE(0, 0);
        __syncthreads();        // drain = cheap (loads issued a full COMPUTE ago)

        // ---- odd tile t0+1 (buf1, set1); stage t0+2 -> buf0 ----
        if (kt2 + 1 < NT / 2) {
            STAGE(0, t0 + 2);
            LOADB(0);
            LOADSZ(kt2 + 1);    // next group's raw s/z
            COMPUTE(1, 1);      // uses group kt2's ssv/zzv
            MAKESZ();           // group kt2+1 (after COMPUTE consumed old ssv/zzv)
        } else {
            COMPUTE(1, 1);
        }
        __syncthreads();
    }

#undef STAGE
#undef LOADB
#undef LOADSZ
#undef MAKESZ
#undef COMPUTE

    // epilogue: C/D layout col = lane&15, row = (lane>>4)*4 + reg
    const int ccol0 = n0 + wc * 64 + lr;
    float bj[4];
#pragma unroll
    for (int j = 0; j < 4; ++j) bj[j] = bias[ccol0 + j * 16];
    const int m0 = mt * BM;
#pragma unroll
    for (int i = 0; i < 8; ++i) {
        const int rbase = m0 + wr * 128 + i * 16 + lk * 4;
#pragma unroll
        for (int j = 0; j < 4; ++j) {
            const int col = ccol0 + j * 16;
#pragma unroll
            for (int r = 0; r < 4; ++r)
                out[(size_t)(rbase + r) * N_DIM + col] = acc[i][j][r] + bj[j];
        }
    }
}

// ================= fallback (R7 kernel, 958 µs proven) for small ws =================
constexpr int FB_BM = 128, FB_BN = 128;
constexpr int FB_NXT = N_DIM / FB_BN;   // 86
constexpr int FB_NWG = FB_NXT * (M_DIM / FB_BM); // 5504

#define BAR() do {                                           \
    asm volatile("s_waitcnt lgkmcnt(0)" ::: "memory");       \
    __builtin_amdgcn_s_barrier();                            \
    __builtin_amdgcn_sched_barrier(0);                       \
} while (0)

__global__ __launch_bounds__(256, 3)
void qgemm_fb_kernel(const float* __restrict__ x, const uint32_t* __restrict__ qw,
                     const uint32_t* __restrict__ qz, const float* __restrict__ sc,
                     const float* __restrict__ bias, float* __restrict__ out)
{
    constexpr int LDA = 72;
    __shared__ _Float16 As[2][FB_BM * LDA];

    const int tid  = threadIdx.x;
    const int lid  = (blockIdx.x & 7) * (FB_NWG / 8) + (blockIdx.x >> 3);
    const int m0   = (lid / FB_NXT) * FB_BM;
    const int n0   = (lid % FB_NXT) * FB_BN;
    const int lane = tid & 63, wid = tid >> 6;
    const int wr = wid >> 1, wc = wid & 1;
    const int lr = lane & 15, lk = lane >> 4;
    const int arow = tid >> 3, acp = tid & 7;

    f32x4 acc[4][4];
#pragma unroll
    for (int i = 0; i < 4; ++i)
#pragma unroll
        for (int j = 0; j < 4; ++j) { f32x4 z = {0.f,0.f,0.f,0.f}; acc[i][j] = z; }

    f32x4    aE[4][2], aO[4][2];
    uint32_t breg[8], bregN[8];
    f16x2    ssv[4], zzv[4];
    float    s_nxt[4];
    uint32_t z_nxt[4];

    const int   ncb = n0 + wc * 64 + lr;
    const int   shz = 4 * (lr & 7);
    const float* xbase = x + (size_t)(m0 + arow) * K_DIM + acp * 8;
    const uint32_t* qp0 = qw + (size_t)lk * N_DIM + ncb;
    const uint32_t* qp1 = qp0 + (size_t)4 * N_DIM;

#define A_LOAD(S, KT) do { const float* ap_ = xbase + (KT) * BK;             \
    _Pragma("unroll") for (int i = 0; i < 4; ++i) {                          \
        const float* src_ = ap_ + (size_t)(i * 32) * K_DIM;                  \
        S[i][0] = *(const f32x4*)(src_);                                     \
        S[i][1] = *(const f32x4*)(src_ + 4); } } while (0)

#define A_WRITE(S, BUF) do {                                                 \
    _Pragma("unroll") for (int i = 0; i < 4; ++i) { H8 v_;                   \
        _Pragma("unroll") for (int j = 0; j < 4; ++j)                        \
            v_.p[j] = __builtin_bit_cast(f16x2,                              \
                __builtin_amdgcn_cvt_pkrtz(S[i][0][j], S[i][1][j]));         \
        *(f16x8*)&As[BUF][(arow + i * 32) * LDA + acp * 8] = v_.v; } } while (0)

#define LOADB() do {                                                         \
    _Pragma("unroll") for (int j = 0; j < 4; ++j) bregN[j]     = qp0[j * 16]; \
    _Pragma("unroll") for (int j = 0; j < 4; ++j) bregN[4 + j] = qp1[j * 16]; \
    qp0 += (size_t)8 * N_DIM; qp1 += (size_t)8 * N_DIM; } while (0)

#define COPYB() do { _Pragma("unroll") for (int q = 0; q < 8; ++q) breg[q] = bregN[q]; } while (0)

#define LOADSZ(g) do { _Pragma("unroll") for (int j = 0; j < 4; ++j) {       \
    s_nxt[j] = sc[(size_t)(g) * N_DIM + ncb + j * 16];                       \
    z_nxt[j] = qz[(size_t)(g) * NZW + (ncb >> 3) + j * 2]; } } while (0)

#define MAKESZ() do { _Pragma("unroll") for (int j = 0; j < 4; ++j) {        \
    _Float16 zh = (_Float16)(float)(1024u + ((z_nxt[j] >> shz) & 15u));      \
    _Float16 sh = (_Float16)s_nxt[j];                                        \
    f16x2 sp = {sh, sh}; ssv[j] = sp;                                        \
    f16x2 zp = {zh, zh}; zzv[j] = zp; } } while (0)

#define COMPUTE(BUF) do {                                                    \
    _Pragma("unroll") for (int ks = 0; ks < 2; ++ks) {                       \
        f16x8 af[4], bf[4];                                                  \
        _Pragma("unroll") for (int i = 0; i < 4; ++i)                        \
            af[i] = *(const f16x8*)&As[BUF][(wr * 64 + i * 16 + lr) * LDA + ks * 32 + lk * 8]; \
        _Pragma("unroll") for (int j = 0; j < 4; ++j)                        \
            bf[j] = dq_word(breg[ks * 4 + j], ssv[j], zzv[j]);               \
        _Pragma("unroll") for (int i = 0; i < 4; ++i)                        \
            _Pragma("unroll") for (int j = 0; j < 4; ++j)                    \
                acc[i][j] = __builtin_amdgcn_mfma_f32_16x16x32_f16(af[i], bf[j], acc[i][j], 0, 0, 0); \
    } } while (0)

    LOADSZ(0);
    A_LOAD(aE, 0);
    LOADB();
    A_WRITE(aE, 0);
    A_LOAD(aO, 1);
    BAR();

    for (int kt2 = 0; kt2 < NT / 2; ++kt2) {
        const int t0 = 2 * kt2;
        MAKESZ();
        COPYB();
        LOADB();
        A_WRITE(aO, 1);
        if (kt2 + 1 < NT / 2) A_LOAD(aE, t0 + 2);
        COMPUTE(0);
        BAR();

        COPYB();
        if (kt2 + 1 < NT / 2) {
            LOADB();
            LOADSZ(kt2 + 1);
            A_WRITE(aE, 0);
            A_LOAD(aO, t0 + 3);
        }
        COMPUTE(1);
        BAR();
    }

#undef A_LOAD
#undef A_WRITE
#undef LOADB
#undef COPYB
#undef LOADSZ
#undef MAKESZ
#undef COMPUTE

    const int ccol0 = n0 + wc * 64 + lr;
    float bj[4];
#pragma unroll
    for (int j = 0; j < 4; ++j) bj[j] = bias[ccol0 + j * 16];
#pragma unroll
    for (int i = 0; i < 4; ++i) {
        const int rbase = m0 + wr * 64 + i * 16 + lk * 4;
#pragma unroll
        for (int j = 0; j < 4; ++j) {
            const int col = ccol0 + j * 16;
#pragma unroll
            for (int r = 0; r < 4; ++r)
                out[(size_t)(rbase + r) * N_DIM + col] = acc[i][j][r] + bj[j];
        }
    }
}

extern "C" void kernel_launch(void* const* d_in, const int* in_sizes, int n_in,
                              void* d_out, int out_size, void* d_ws, size_t ws_size,
                              hipStream_t stream) {
    const float*    xp = (const float*)d_in[0];
    const uint32_t* qw = (const uint32_t*)d_in[1];
    const uint32_t* qz = (const uint32_t*)d_in[2];
    const float*    sc = (const float*)d_in[3];
    const float*    bi = (const float*)d_in[4];
    float*          op = (float*)d_out;
    (void)in_sizes; (void)n_in; (void)out_size;

    const size_t need = (size_t)M_DIM * K_DIM * sizeof(_Float16); // 64 MiB
    if (ws_size >= need) {
        prep_kernel<<<dim3(MXT * NT), dim3(512), 0, stream>>>(xp, (_Float16*)d_ws);
        qgemm256_kernel<<<dim3(NWG), dim3(512), 0, stream>>>((const _Float16*)d_ws, qw, qz, sc, bi, op);
    } else {
        qgemm_fb_kernel<<<dim3(FB_NWG), dim3(256), 0, stream>>>(xp, qw, qz, sc, bi, op);
    }
}

// Round 11
// 4064.039 us; speedup vs baseline: 1.3200x; 1.0205x over previous
//
#include <hip/hip_runtime.h>
#include <stdint.h>

#define K_DIM 4096
#define N_DIM 11008
#define M_DIM 8192

constexpr int BM = 256, BN = 128, BK = 64;
constexpr int NT  = K_DIM / BK;      // 64
constexpr int NZW = N_DIM / 8;       // 1376
constexpr int NXT = N_DIM / BN;      // 86
constexpr int MXT = M_DIM / BM;      // 32
constexpr int NWG = NXT * MXT;       // 2752 = 8 * 344
constexpr int TILE_ELEMS = BM * BK;  // 16384 f16 = 32 KiB per K-tile

typedef _Float16 f16x2 __attribute__((ext_vector_type(2)));
typedef _Float16 f16x8 __attribute__((ext_vector_type(8)));
typedef float    f32x4 __attribute__((ext_vector_type(4)));
union H8 { f16x8 v; f16x2 p[4]; };

// word w holds nibbles for k-offsets 0..7; output k-order (0,4,1,5,2,6,3,7).
// Exact: (1024+q) - (1024+z) is Sterbenz-exact; single rounding on *s.
__device__ __forceinline__ f16x8 dq_word(uint32_t w, f16x2 ss, f16x2 zz) {
    H8 r;
    uint32_t t0 = ( w        & 0x000F000Fu) | 0x64006400u;
    uint32_t t1 = ((w >> 4)  & 0x000F000Fu) | 0x64006400u;
    uint32_t t2 = ((w >> 8)  & 0x000F000Fu) | 0x64006400u;
    uint32_t t3 = ((w >> 12) & 0x000F000Fu) | 0x64006400u;
    r.p[0] = (__builtin_bit_cast(f16x2, t0) - zz) * ss;
    r.p[1] = (__builtin_bit_cast(f16x2, t1) - zz) * ss;
    r.p[2] = (__builtin_bit_cast(f16x2, t2) - zz) * ss;
    r.p[3] = (__builtin_bit_cast(f16x2, t3) - zz) * ss;
    return r.v;
}

// ========= pre-pass: x fp32 -> f16, fragment-major 256-row tiles =========
// x16 layout: [mt(32)][kt(64)][fk(8)][row(256)][octet(8)], octet holds pairs
// (e, e+4) of k = kt*64 + fk*8 + e  (matches dq_word's output permutation).
__global__ __launch_bounds__(512)
void prep_kernel(const float* __restrict__ x, _Float16* __restrict__ x16) {
    const int b  = blockIdx.x;          // mt*64 + kt
    const int mt = b >> 6, kt = b & 63;
    _Float16* dst = x16 + (size_t)b * TILE_ELEMS;
#pragma unroll
    for (int it = 0; it < 4; ++it) {
        const int o   = it * 512 + threadIdx.x;   // 0..2047 = fk*256 + row
        const int fk  = o >> 8, row = o & 255;
        const float* src = x + (size_t)(mt * 256 + row) * K_DIM + kt * 64 + fk * 8;
        f32x4 a0 = *(const f32x4*)src;
        f32x4 a1 = *(const f32x4*)(src + 4);
        H8 v;
#pragma unroll
        for (int j = 0; j < 4; ++j)
            v.p[j] = __builtin_bit_cast(f16x2, __builtin_amdgcn_cvt_pkrtz(a0[j], a1[j]));
        *(f16x8*)(dst + (size_t)o * 8) = v.v;
    }
}

// ===== 256x128 tile, 4 waves (2M x 2N), wave-tile 128x64; A via global_load_lds dbuf =====
// 256-thread block: per-wave reg budget 256 at 2 waves/EU -> acc(128) + ~90
// working set fits (the 512-thread variants R8-R10 structurally spilled).
__global__ __launch_bounds__(256, 2)
void qgemm256_kernel(const _Float16* __restrict__ x16, const uint32_t* __restrict__ qw,
                     const uint32_t* __restrict__ qz, const float* __restrict__ sc,
                     const float* __restrict__ bias, float* __restrict__ out)
{
    __shared__ _Float16 As[2 * TILE_ELEMS];   // 2 x 32 KiB, fragment-major, linear

    const int tid  = threadIdx.x;
    const int lid  = (blockIdx.x & 7) * (NWG / 8) + (blockIdx.x >> 3); // XCD swizzle
    const int mt   = lid / NXT;
    const int n0   = (lid % NXT) * BN;

    const int lane = tid & 63, wid = tid >> 6;   // wid 0..3
    const int wr = wid >> 1;          // 0..1  (M, 128 rows)
    const int wc = wid & 1;           // 0..1  (N, 64 cols)
    const int lr = lane & 15, lk = lane >> 4;

    f32x4 acc[8][4];
#pragma unroll
    for (int i = 0; i < 8; ++i)
#pragma unroll
        for (int j = 0; j < 4; ++j) {
            f32x4 z = {0.f, 0.f, 0.f, 0.f};
            acc[i][j] = z;
        }

    uint32_t breg[2][8];
    f16x2    ssv[4], zzv[4];
    float    s_nxt[4];
    uint32_t z_nxt[4];

    const int ncb = n0 + wc * 64 + lr;
    const int shz = 4 * (lr & 7);

    const _Float16* xsrc = x16 + (size_t)mt * (64 * TILE_ELEMS) + tid * 8;
    const uint32_t* qp0 = qw + (size_t)lk * N_DIM + ncb;
    const uint32_t* qp1 = qp0 + (size_t)4 * N_DIM;

// 256 threads x 8 DMAs x 16 B = 32 KiB tile; DMA 'it' covers fragment fk=it/...:
// elem offset = it*2048 + tid*8 -> [fk = it][row = tid][octet]  (linear, no swizzle)
#define STAGE(BUF, KT) do {                                                  \
    const _Float16* s_ = xsrc + (size_t)(KT) * TILE_ELEMS;                   \
    _Float16* d_ = &As[(BUF) * TILE_ELEMS + tid * 8];                        \
    _Pragma("unroll") for (int it = 0; it < 8; ++it)                         \
        __builtin_amdgcn_global_load_lds(                                    \
            (const __attribute__((address_space(1))) void*)(s_ + it * 2048), \
            (__attribute__((address_space(3))) void*)(d_ + it * 2048), 16, 0, 0); \
    } while (0)

#define LOADB(SET) do {                                                      \
    _Pragma("unroll") for (int j = 0; j < 4; ++j) breg[SET][j]     = qp0[j * 16]; \
    _Pragma("unroll") for (int j = 0; j < 4; ++j) breg[SET][4 + j] = qp1[j * 16]; \
    qp0 += (size_t)8 * N_DIM; qp1 += (size_t)8 * N_DIM; } while (0)

#define LOADSZ(g) do { _Pragma("unroll") for (int j = 0; j < 4; ++j) {       \
    s_nxt[j] = sc[(size_t)(g) * N_DIM + ncb + j * 16];                       \
    z_nxt[j] = qz[(size_t)(g) * NZW + (ncb >> 3) + j * 2]; } } while (0)

#define MAKESZ() do { _Pragma("unroll") for (int j = 0; j < 4; ++j) {        \
    _Float16 zh = (_Float16)(float)(1024u + ((z_nxt[j] >> shz) & 15u));      \
    _Float16 sh = (_Float16)s_nxt[j];                                        \
    f16x2 sp = {sh, sh}; ssv[j] = sp;                                        \
    f16x2 zp = {zh, zh}; zzv[j] = zp; } } while (0)

#define COMPUTE(BUF, SET) do {                                               \
    _Pragma("unroll") for (int ks = 0; ks < 2; ++ks) {                       \
        f16x8 bf[4];                                                         \
        _Pragma("unroll") for (int j = 0; j < 4; ++j)                        \
            bf[j] = dq_word(breg[SET][ks * 4 + j], ssv[j], zzv[j]);          \
        _Pragma("unroll") for (int i = 0; i < 8; ++i) {                      \
            f16x8 af_ = *(const f16x8*)&As[(BUF) * TILE_ELEMS                \
                + (ks * 4 + lk) * 2048 + (wr * 128 + i * 16 + lr) * 8];      \
            _Pragma("unroll") for (int j = 0; j < 4; ++j)                    \
                acc[i][j] = __builtin_amdgcn_mfma_f32_16x16x32_f16(af_, bf[j], acc[i][j], 0, 0, 0); \
        } } } while (0)

    // ---------------- prologue ----------------
    LOADSZ(0);
    STAGE(0, 0);
    LOADB(0);
    MAKESZ();
    __syncthreads();    // vmcnt(0) drain: tile-0 DMA complete

    for (int kt2 = 0; kt2 < NT / 2; ++kt2) {
        const int t0 = 2 * kt2;
        // ---- even tile t0 (buf0, set0); stage t0+1 -> buf1 ----
        STAGE(1, t0 + 1);       // DMA issued, lands during COMPUTE
        LOADB(1);               // B(t0+1) in flight during COMPUTE
        COMPUTE(0, 0);
        __syncthreads();        // drain cheap: loads issued a full COMPUTE ago

        // ---- odd tile t0+1 (buf1, set1); stage t0+2 -> buf0 ----
        if (kt2 + 1 < NT / 2) {
            STAGE(0, t0 + 2);
            LOADB(0);
            LOADSZ(kt2 + 1);    // next group's raw s/z
            COMPUTE(1, 1);      // uses group kt2's ssv/zzv
            MAKESZ();           // group kt2+1 (after COMPUTE consumed old ssv/zzv)
        } else {
            COMPUTE(1, 1);
        }
        __syncthreads();
    }

#undef STAGE
#undef LOADB
#undef LOADSZ
#undef MAKESZ
#undef COMPUTE

    // epilogue: C/D layout col = lane&15, row = (lane>>4)*4 + reg
    const int ccol0 = n0 + wc * 64 + lr;
    float bj[4];
#pragma unroll
    for (int j = 0; j < 4; ++j) bj[j] = bias[ccol0 + j * 16];
    const int m0 = mt * BM;
#pragma unroll
    for (int i = 0; i < 8; ++i) {
        const int rbase = m0 + wr * 128 + i * 16 + lk * 4;
#pragma unroll
        for (int j = 0; j < 4; ++j) {
            const int col = ccol0 + j * 16;
#pragma unroll
            for (int r = 0; r < 4; ++r)
                out[(size_t)(rbase + r) * N_DIM + col] = acc[i][j][r] + bj[j];
        }
    }
}

// ================= fallback (R7 kernel, 958 µs proven) for small ws =================
constexpr int FB_BM = 128, FB_BN = 128;
constexpr int FB_NXT = N_DIM / FB_BN;   // 86
constexpr int FB_NWG = FB_NXT * (M_DIM / FB_BM); // 5504

#define BAR() do {                                           \
    asm volatile("s_waitcnt lgkmcnt(0)" ::: "memory");       \
    __builtin_amdgcn_s_barrier();                            \
    __builtin_amdgcn_sched_barrier(0);                       \
} while (0)

__global__ __launch_bounds__(256, 3)
void qgemm_fb_kernel(const float* __restrict__ x, const uint32_t* __restrict__ qw,
                     const uint32_t* __restrict__ qz, const float* __restrict__ sc,
                     const float* __restrict__ bias, float* __restrict__ out)
{
    constexpr int LDA = 72;
    __shared__ _Float16 As[2][FB_BM * LDA];

    const int tid  = threadIdx.x;
    const int lid  = (blockIdx.x & 7) * (FB_NWG / 8) + (blockIdx.x >> 3);
    const int m0   = (lid / FB_NXT) * FB_BM;
    const int n0   = (lid % FB_NXT) * FB_BN;
    const int lane = tid & 63, wid = tid >> 6;
    const int wr = wid >> 1, wc = wid & 1;
    const int lr = lane & 15, lk = lane >> 4;
    const int arow = tid >> 3, acp = tid & 7;

    f32x4 acc[4][4];
#pragma unroll
    for (int i = 0; i < 4; ++i)
#pragma unroll
        for (int j = 0; j < 4; ++j) { f32x4 z = {0.f,0.f,0.f,0.f}; acc[i][j] = z; }

    f32x4    aE[4][2], aO[4][2];
    uint32_t breg[8], bregN[8];
    f16x2    ssv[4], zzv[4];
    float    s_nxt[4];
    uint32_t z_nxt[4];

    const int   ncb = n0 + wc * 64 + lr;
    const int   shz = 4 * (lr & 7);
    const float* xbase = x + (size_t)(m0 + arow) * K_DIM + acp * 8;
    const uint32_t* qp0 = qw + (size_t)lk * N_DIM + ncb;
    const uint32_t* qp1 = qp0 + (size_t)4 * N_DIM;

#define A_LOAD(S, KT) do { const float* ap_ = xbase + (KT) * BK;             \
    _Pragma("unroll") for (int i = 0; i < 4; ++i) {                          \
        const float* src_ = ap_ + (size_t)(i * 32) * K_DIM;                  \
        S[i][0] = *(const f32x4*)(src_);                                     \
        S[i][1] = *(const f32x4*)(src_ + 4); } } while (0)

#define A_WRITE(S, BUF) do {                                                 \
    _Pragma("unroll") for (int i = 0; i < 4; ++i) { H8 v_;                   \
        _Pragma("unroll") for (int j = 0; j < 4; ++j)                        \
            v_.p[j] = __builtin_bit_cast(f16x2,                              \
                __builtin_amdgcn_cvt_pkrtz(S[i][0][j], S[i][1][j]));         \
        *(f16x8*)&As[BUF][(arow + i * 32) * LDA + acp * 8] = v_.v; } } while (0)

#define LOADB() do {                                                         \
    _Pragma("unroll") for (int j = 0; j < 4; ++j) bregN[j]     = qp0[j * 16]; \
    _Pragma("unroll") for (int j = 0; j < 4; ++j) bregN[4 + j] = qp1[j * 16]; \
    qp0 += (size_t)8 * N_DIM; qp1 += (size_t)8 * N_DIM; } while (0)

#define COPYB() do { _Pragma("unroll") for (int q = 0; q < 8; ++q) breg[q] = bregN[q]; } while (0)

#define LOADSZ(g) do { _Pragma("unroll") for (int j = 0; j < 4; ++j) {       \
    s_nxt[j] = sc[(size_t)(g) * N_DIM + ncb + j * 16];                       \
    z_nxt[j] = qz[(size_t)(g) * NZW + (ncb >> 3) + j * 2]; } } while (0)

#define MAKESZ() do { _Pragma("unroll") for (int j = 0; j < 4; ++j) {        \
    _Float16 zh = (_Float16)(float)(1024u + ((z_nxt[j] >> shz) & 15u));      \
    _Float16 sh = (_Float16)s_nxt[j];                                        \
    f16x2 sp = {sh, sh}; ssv[j] = sp;                                        \
    f16x2 zp = {zh, zh}; zzv[j] = zp; } } while (0)

#define COMPUTE(BUF) do {                                                    \
    _Pragma("unroll") for (int ks = 0; ks < 2; ++ks) {                       \
        f16x8 af[4], bf[4];                                                  \
        _Pragma("unroll") for (int i = 0; i < 4; ++i)                        \
            af[i] = *(const f16x8*)&As[BUF][(wr * 64 + i * 16 + lr) * LDA + ks * 32 + lk * 8]; \
        _Pragma("unroll") for (int j = 0; j < 4; ++j)                        \
            bf[j] = dq_word(breg[ks * 4 + j], ssv[j], zzv[j]);               \
        _Pragma("unroll") for (int i = 0; i < 4; ++i)                        \
            _Pragma("unroll") for (int j = 0; j < 4; ++j)                    \
                acc[i][j] = __builtin_amdgcn_mfma_f32_16x16x32_f16(af[i], bf[j], acc[i][j], 0, 0, 0); \
    } } while (0)

    LOADSZ(0);
    A_LOAD(aE, 0);
    LOADB();
    A_WRITE(aE, 0);
    A_LOAD(aO, 1);
    BAR();

    for (int kt2 = 0; kt2 < NT / 2; ++kt2) {
        const int t0 = 2 * kt2;
        MAKESZ();
        COPYB();
        LOADB();
        A_WRITE(aO, 1);
        if (kt2 + 1 < NT / 2) A_LOAD(aE, t0 + 2);
        COMPUTE(0);
        BAR();

        COPYB();
        if (kt2 + 1 < NT / 2) {
            LOADB();
            LOADSZ(kt2 + 1);
            A_WRITE(aE, 0);
            A_LOAD(aO, t0 + 3);
        }
        COMPUTE(1);
        BAR();
    }

#undef A_LOAD
#undef A_WRITE
#undef LOADB
#undef COPYB
#undef LOADSZ
#undef MAKESZ
#undef COMPUTE

    const int ccol0 = n0 + wc * 64 + lr;
    float bj[4];
#pragma unroll
    for (int j = 0; j < 4; ++j) bj[j] = bias[ccol0 + j * 16];
#pragma unroll
    for (int i = 0; i < 4; ++i) {
        const int rbase = m0 + wr * 64 + i * 16 + lk * 4;
#pragma unroll
        for (int j = 0; j < 4; ++j) {
            const int col = ccol0 + j * 16;
#pragma unroll
            for (int r = 0; r < 4; ++r)
                out[(size_t)(rbase + r) * N_DIM + col] = acc[i][j][r] + bj[j];
        }
    }
}

extern "C" void kernel_launch(void* const* d_in, const int* in_sizes, int n_in,
                              void* d_out, int out_size, void* d_ws, size_t ws_size,
                              hipStream_t stream) {
    const float*    xp = (const float*)d_in[0];
    const uint32_t* qw = (const uint32_t*)d_in[1];
    const uint32_t* qz = (const uint32_t*)d_in[2];
    const float*    sc = (const float*)d_in[3];
    const float*    bi = (const float*)d_in[4];
    float*          op = (float*)d_out;
    (void)in_sizes; (void)n_in; (void)out_size;

    const size_t need = (size_t)M_DIM * K_DIM * sizeof(_Float16); // 64 MiB
    if (ws_size >= need) {
        prep_kernel<<<dim3(MXT * NT), dim3(512), 0, stream>>>(xp, (_Float16*)d_ws);
        qgemm256_kernel<<<dim3(NWG), dim3(256), 0, stream>>>((const _Float16*)d_ws, qw, qz, sc, bi, op);
    } else {
        qgemm_fb_kernel<<<dim3(FB_NWG), dim3(256), 0, stream>>>(xp, qw, qz, sc, bi, op);
    }
}

// Round 12
// 1468.156 us; speedup vs baseline: 3.6538x; 2.7681x over previous
//
#include <hip/hip_runtime.h>
#include <stdint.h>

#define K_DIM 4096
#define N_DIM 11008
#define M_DIM 8192

constexpr int NT  = 64;                  // K tiles of 64
constexpr int NZW = N_DIM / 8;           // 1376
constexpr int NXT = N_DIM / 128;         // 86
constexpr int NWG = NXT * (M_DIM / 128); // 5504 = 8 * 688
constexpr int LDA = 72;                  // f16 elems per LDS row (144 B, bank-uniform)
constexpr int WBUF = 32 * LDA;           // elems per wave buffer

typedef _Float16 f16x2 __attribute__((ext_vector_type(2)));
typedef _Float16 f16x8 __attribute__((ext_vector_type(8)));
typedef float    f32x4 __attribute__((ext_vector_type(4)));
union H8 { f16x8 v; f16x2 p[4]; };

// word w holds nibbles for k-offsets 0..7; output k-order (0,4,1,5,2,6,3,7).
// Exact: (1024+q) - (1024+z) is Sterbenz-exact; single rounding on *s.
__device__ __forceinline__ f16x8 dq_word(uint32_t w, f16x2 ss, f16x2 zz) {
    H8 r;
    uint32_t t0 = ( w        & 0x000F000Fu) | 0x64006400u;
    uint32_t t1 = ((w >> 4)  & 0x000F000Fu) | 0x64006400u;
    uint32_t t2 = ((w >> 8)  & 0x000F000Fu) | 0x64006400u;
    uint32_t t3 = ((w >> 12) & 0x000F000Fu) | 0x64006400u;
    r.p[0] = (__builtin_bit_cast(f16x2, t0) - zz) * ss;
    r.p[1] = (__builtin_bit_cast(f16x2, t1) - zz) * ss;
    r.p[2] = (__builtin_bit_cast(f16x2, t2) - zz) * ss;
    r.p[3] = (__builtin_bit_cast(f16x2, t3) - zz) * ss;
    return r.v;
}

// ===== barrier-free kernel: 4 waves x wave-tile 32x128, wave-private LDS =====
// Each wave owns rows [m0 + wid*32, +32) and ALL 128 cols of the block tile.
// A: wave stages its own rows f32->f16 into a private LDS dbuf (reg-staged,
// 16 f32 regs per half-K). B: reg-dequanted per lane (R7-proven machinery,
// WN=128 -> 16 words/lane/tile). No __syncthreads anywhere: the only ordering
// is same-wave vmcnt/lgkmcnt, which the compiler inserts correctly.
__global__ __launch_bounds__(256)
void qgemm_kernel(const float* __restrict__ x, const uint32_t* __restrict__ qw,
                  const uint32_t* __restrict__ qz, const float* __restrict__ sc,
                  const float* __restrict__ bias, float* __restrict__ out)
{
    __shared__ _Float16 As[4][2][WBUF];   // per-wave private dbuf, 36,864 B total

    const int tid  = threadIdx.x;
    const int lid  = (blockIdx.x & 7) * (NWG / 8) + (blockIdx.x >> 3); // XCD swizzle
    const int m0   = (lid / NXT) * 128;
    const int n0   = (lid % NXT) * 128;

    const int lane = tid & 63, wid = tid >> 6;
    const int lr = lane & 15, lk = lane >> 4;
    const int r  = lane >> 1, c  = lane & 1;   // staging: row 0..31, 64B-half

    f32x4 acc[2][8];
#pragma unroll
    for (int i = 0; i < 2; ++i)
#pragma unroll
        for (int j = 0; j < 8; ++j) {
            f32x4 z = {0.f, 0.f, 0.f, 0.f};
            acc[i][j] = z;
        }

    f32x4    g0, g1, g2, g3;          // in-flight A half-tile (16 regs)
    uint32_t breg[2][16];
    f16x2    ssv[8], zzv[8];
    float    s_nxt[8];
    uint32_t z_nxt[8];

    const int ncb = n0 + lr;          // this lane's base column (cols ncb + j*16)
    const int shz = 4 * (lr & 7);     // qzeros nibble shift (n0 % 8 == 0)

    const float* xst = x + (size_t)(m0 + wid * 32 + r) * K_DIM + c * 16;
    const uint32_t* qp0 = qw + (size_t)lk * N_DIM + ncb;   // k-row lk   (ks=0)
    const uint32_t* qp1 = qp0 + (size_t)4 * N_DIM;         // k-row lk+4 (ks=1)
    _Float16* lds = &As[wid][0][0];

#define A_ISSUE(KT, KS) do { const float* p_ = xst + (KT) * 64 + (KS) * 32;  \
    g0 = *(const f32x4*)(p_);      g1 = *(const f32x4*)(p_ + 4);             \
    g2 = *(const f32x4*)(p_ + 8);  g3 = *(const f32x4*)(p_ + 12); } while (0)

// octet pairs (e, e+4) match dq_word's k-permutation (R2-proven)
#define A_WRITE(BUF, KS) do { H8 va_, vb_;                                   \
    _Pragma("unroll") for (int j = 0; j < 4; ++j) {                          \
        va_.p[j] = __builtin_bit_cast(f16x2,                                 \
                     __builtin_amdgcn_cvt_pkrtz(g0[j], g1[j]));              \
        vb_.p[j] = __builtin_bit_cast(f16x2,                                 \
                     __builtin_amdgcn_cvt_pkrtz(g2[j], g3[j])); }            \
    _Float16* d_ = lds + (BUF) * WBUF + r * LDA + (KS) * 32 + c * 16;        \
    *(f16x8*)(d_)     = va_.v;                                               \
    *(f16x8*)(d_ + 8) = vb_.v; } while (0)

#define LOADB(SET) do {                                                      \
    _Pragma("unroll") for (int j = 0; j < 8; ++j) breg[SET][j]     = qp0[j * 16]; \
    _Pragma("unroll") for (int j = 0; j < 8; ++j) breg[SET][8 + j] = qp1[j * 16]; \
    qp0 += (size_t)8 * N_DIM; qp1 += (size_t)8 * N_DIM; } while (0)

#define LOADSZ(G) do { _Pragma("unroll") for (int j = 0; j < 8; ++j) {       \
    s_nxt[j] = sc[(size_t)(G) * N_DIM + ncb + j * 16];                       \
    z_nxt[j] = qz[(size_t)(G) * NZW + (ncb >> 3) + j * 2]; } } while (0)

#define MAKESZ() do { _Pragma("unroll") for (int j = 0; j < 8; ++j) {        \
    _Float16 zh = (_Float16)(float)(1024u + ((z_nxt[j] >> shz) & 15u));      \
    _Float16 sh = (_Float16)s_nxt[j];                                        \
    f16x2 sp = {sh, sh}; ssv[j] = sp;                                        \
    f16x2 zp = {zh, zh}; zzv[j] = zp; } } while (0)

    f16x8 af00, af10, af01, af11;     // A frags: af<i><ks>, rows i*16+lr
#define FRAGS(BUF) do { const _Float16* b_ = lds + (BUF) * WBUF + lr * LDA;  \
    af00 = *(const f16x8*)(b_ + lk * 8);                                     \
    af10 = *(const f16x8*)(b_ + 16 * LDA + lk * 8);                          \
    af01 = *(const f16x8*)(b_ + 32 + lk * 8);                                \
    af11 = *(const f16x8*)(b_ + 16 * LDA + 32 + lk * 8); } while (0)

#define COMPUTE_KS(SET, KS) do {                                             \
    _Pragma("unroll") for (int j = 0; j < 8; ++j) {                          \
        f16x8 bf_ = dq_word(breg[SET][(KS) * 8 + j], ssv[j], zzv[j]);        \
        acc[0][j] = __builtin_amdgcn_mfma_f32_16x16x32_f16(                  \
                        (KS) ? af01 : af00, bf_, acc[0][j], 0, 0, 0);        \
        acc[1][j] = __builtin_amdgcn_mfma_f32_16x16x32_f16(                  \
                        (KS) ? af11 : af10, bf_, acc[1][j], 0, 0, 0);        \
    } } while (0)

    // ---------------- prologue (tile 0 -> buf0, group 0) ----------------
    LOADSZ(0); MAKESZ();
    A_ISSUE(0, 0); A_WRITE(0, 0);
    A_ISSUE(0, 1); A_WRITE(0, 1);
    LOADB(0);

    for (int kt2 = 0; kt2 < NT / 2; ++kt2) {
        const int t = 2 * kt2;
        // ---- even tile t: buf0, set0; stage t+1 -> buf1 ----
        FRAGS(0);                       // lgkm: same-wave writes from last iter
        A_ISSUE(t + 1, 0);              // in flight under COMPUTE
        LOADB(1);                       // B(t+1) in flight
        if (kt2 + 1 < NT / 2) LOADSZ(kt2 + 1);   // next group's raw s/z
        COMPUTE_KS(0, 0);
        A_WRITE(1, 0);                  // vm-wait hidden by COMPUTE above
        A_ISSUE(t + 1, 1);
        COMPUTE_KS(0, 1);
        A_WRITE(1, 1);

        // ---- odd tile t+1: buf1, set1; stage t+2 -> buf0 ----
        FRAGS(1);
        if (kt2 + 1 < NT / 2) { A_ISSUE(t + 2, 0); LOADB(0); }
        COMPUTE_KS(1, 0);
        if (kt2 + 1 < NT / 2) { A_WRITE(0, 0); A_ISSUE(t + 2, 1); }
        COMPUTE_KS(1, 1);
        if (kt2 + 1 < NT / 2) { A_WRITE(0, 1); MAKESZ(); }  // group kt2+1
    }

#undef A_ISSUE
#undef A_WRITE
#undef LOADB
#undef LOADSZ
#undef MAKESZ
#undef FRAGS
#undef COMPUTE_KS

    // epilogue: C/D layout col = lane&15, row = (lane>>4)*4 + reg
    const int ccol0 = n0 + lr;
    float bj[8];
#pragma unroll
    for (int j = 0; j < 8; ++j) bj[j] = bias[ccol0 + j * 16];
    const int rb0 = m0 + wid * 32 + lk * 4;
#pragma unroll
    for (int i = 0; i < 2; ++i) {
#pragma unroll
        for (int j = 0; j < 8; ++j) {
            const int col = ccol0 + j * 16;
#pragma unroll
            for (int rr = 0; rr < 4; ++rr)
                out[(size_t)(rb0 + i * 16 + rr) * N_DIM + col] = acc[i][j][rr] + bj[j];
        }
    }
}

extern "C" void kernel_launch(void* const* d_in, const int* in_sizes, int n_in,
                              void* d_out, int out_size, void* d_ws, size_t ws_size,
                              hipStream_t stream) {
    const float*    xp = (const float*)d_in[0];
    const uint32_t* qw = (const uint32_t*)d_in[1];
    const uint32_t* qz = (const uint32_t*)d_in[2];
    const float*    sc = (const float*)d_in[3];
    const float*    bi = (const float*)d_in[4];
    float*          op = (float*)d_out;
    (void)in_sizes; (void)n_in; (void)d_ws; (void)ws_size; (void)out_size;

    qgemm_kernel<<<dim3(NWG), dim3(256), 0, stream>>>(xp, qw, qz, sc, bi, op);
}

// Round 13
// 916.488 us; speedup vs baseline: 5.8532x; 1.6019x over previous
//
#include <hip/hip_runtime.h>
#include <stdint.h>

#define K_DIM 4096
#define N_DIM 11008
#define M_DIM 8192

constexpr int BM = 128, BN = 128, BK = 64;
constexpr int LDA = 72;            // f16 elems/row: 144 B stride (R2/R7-proven)
constexpr int NT  = K_DIM / BK;    // 64
constexpr int NZW = N_DIM / 8;     // 1376
constexpr int NXT = N_DIM / BN;    // 86
constexpr int NWG = NXT * (M_DIM / BM);  // 5504 = 8 * 688

typedef _Float16 f16x2 __attribute__((ext_vector_type(2)));
typedef _Float16 f16x8 __attribute__((ext_vector_type(8)));
typedef float    f32x4 __attribute__((ext_vector_type(4)));
union H8 { f16x8 v; f16x2 p[4]; };

// word w holds nibbles for k-offsets 0..7; output k-order (0,4,1,5,2,6,3,7).
// Exact: (1024+q) - (1024+z) is Sterbenz-exact; single rounding on *s.
__device__ __forceinline__ f16x8 dq_word(uint32_t w, f16x2 ss, f16x2 zz) {
    H8 r;
    uint32_t t0 = ( w        & 0x000F000Fu) | 0x64006400u;
    uint32_t t1 = ((w >> 4)  & 0x000F000Fu) | 0x64006400u;
    uint32_t t2 = ((w >> 8)  & 0x000F000Fu) | 0x64006400u;
    uint32_t t3 = ((w >> 12) & 0x000F000Fu) | 0x64006400u;
    r.p[0] = (__builtin_bit_cast(f16x2, t0) - zz) * ss;
    r.p[1] = (__builtin_bit_cast(f16x2, t1) - zz) * ss;
    r.p[2] = (__builtin_bit_cast(f16x2, t2) - zz) * ss;
    r.p[3] = (__builtin_bit_cast(f16x2, t3) - zz) * ss;
    return r.v;
}

// No-drain barrier (R7-proven): lgkmcnt(0) for cross-wave LDS visibility,
// raw s_barrier, sched_barrier fence (rule #18). Global loads stay in flight.
#define BAR() do {                                           \
    asm volatile("s_waitcnt lgkmcnt(0)" ::: "memory");       \
    __builtin_amdgcn_s_barrier();                            \
    __builtin_amdgcn_sched_barrier(0);                       \
} while (0)

// ===== 128x128 tile, 4 waves side-by-side in N; wave-tile 128x32 =====
// dq scaling law: per wave-tile, dq-VALU ∝ N_w, A-LDS-reads ∝ M_w, acc=M_w*N_w/64.
// 128x32 minimizes dq at acc=64 (R12's 32x128 maximized it — 2x regression).
__global__ __launch_bounds__(256, 2)
void qgemm_kernel(const float* __restrict__ x, const uint32_t* __restrict__ qw,
                  const uint32_t* __restrict__ qz, const float* __restrict__ sc,
                  const float* __restrict__ bias, float* __restrict__ out)
{
    __shared__ _Float16 As[2][BM * LDA];   // 2 x 18 KiB

    const int tid  = threadIdx.x;
    const int lid  = (blockIdx.x & 7) * (NWG / 8) + (blockIdx.x >> 3); // XCD swizzle
    const int m0   = (lid / NXT) * BM;
    const int n0   = (lid % NXT) * BN;

    const int lane = tid & 63, wid = tid >> 6;   // wid 0..3 = N slot
    const int lr = lane & 15, lk = lane >> 4;

    const int arow = tid >> 3;        // A staging row (0..31, +i*32)
    const int acp  = tid & 7;         // A staging col-octet

    f32x4 acc[8][2];
#pragma unroll
    for (int i = 0; i < 8; ++i)
#pragma unroll
        for (int j = 0; j < 2; ++j) {
            f32x4 z = {0.f, 0.f, 0.f, 0.f};
            acc[i][j] = z;
        }

    f32x4    aS[4][2];                // single A staging set (32 regs)
    uint32_t breg[2][4];              // [set][ks*2+j]
    f16x2    ssv[2], zzv[2];
    float    s_nxt[2];
    uint32_t z_nxt[2];

    const int ncb = n0 + wid * 32 + lr;   // lane's base col; covers ncb, ncb+16
    const int shz = 4 * (lr & 7);
    const float* xbase = x + (size_t)(m0 + arow) * K_DIM + acp * 8;

    const uint32_t* qp0 = qw + (size_t)lk * N_DIM + ncb;   // ks=0 word row
    const uint32_t* qp1 = qp0 + (size_t)4 * N_DIM;         // ks=1 word row

#define A_LOAD(KT) do { const float* ap_ = xbase + (KT) * BK;                \
    _Pragma("unroll") for (int i = 0; i < 4; ++i) {                          \
        const float* src_ = ap_ + (size_t)(i * 32) * K_DIM;                  \
        aS[i][0] = *(const f32x4*)(src_);                                    \
        aS[i][1] = *(const f32x4*)(src_ + 4); } } while (0)

#define A_WRITE(BUF) do {                                                    \
    _Pragma("unroll") for (int i = 0; i < 4; ++i) { H8 v_;                   \
        _Pragma("unroll") for (int j = 0; j < 4; ++j)                        \
            v_.p[j] = __builtin_bit_cast(f16x2,                              \
                __builtin_amdgcn_cvt_pkrtz(aS[i][0][j], aS[i][1][j]));       \
        *(f16x8*)&As[BUF][(arow + i * 32) * LDA + acp * 8] = v_.v; } } while (0)

#define LOADB(SET) do {                                                      \
    breg[SET][0] = qp0[0];  breg[SET][1] = qp0[16];                          \
    breg[SET][2] = qp1[0];  breg[SET][3] = qp1[16];                          \
    qp0 += (size_t)8 * N_DIM; qp1 += (size_t)8 * N_DIM; } while (0)

#define LOADSZ(G) do { _Pragma("unroll") for (int j = 0; j < 2; ++j) {       \
    s_nxt[j] = sc[(size_t)(G) * N_DIM + ncb + j * 16];                       \
    z_nxt[j] = qz[(size_t)(G) * NZW + (ncb >> 3) + j * 2]; } } while (0)

#define MAKESZ() do { _Pragma("unroll") for (int j = 0; j < 2; ++j) {        \
    _Float16 zh = (_Float16)(float)(1024u + ((z_nxt[j] >> shz) & 15u));      \
    _Float16 sh = (_Float16)s_nxt[j];                                        \
    f16x2 sp = {sh, sh}; ssv[j] = sp;                                        \
    f16x2 zp = {zh, zh}; zzv[j] = zp; } } while (0)

// wave spans ALL 128 rows (i=0..7), 32 cols (j=0..1)
#define COMPUTE(BUF, SET) do {                                               \
    _Pragma("unroll") for (int ks = 0; ks < 2; ++ks) {                       \
        f16x8 bf0 = dq_word(breg[SET][ks * 2],     ssv[0], zzv[0]);          \
        f16x8 bf1 = dq_word(breg[SET][ks * 2 + 1], ssv[1], zzv[1]);          \
        _Pragma("unroll") for (int i = 0; i < 8; ++i) {                      \
            f16x8 af_ = *(const f16x8*)&As[BUF][(i * 16 + lr) * LDA + ks * 32 + lk * 8]; \
            acc[i][0] = __builtin_amdgcn_mfma_f32_16x16x32_f16(af_, bf0, acc[i][0], 0, 0, 0); \
            acc[i][1] = __builtin_amdgcn_mfma_f32_16x16x32_f16(af_, bf1, acc[i][1], 0, 0, 0); \
        } } } while (0)

    // ---------------- prologue: tile 0 -> buf0, B(0) -> set0, group 0 ----------------
    LOADSZ(0);
    A_LOAD(0);
    LOADB(0);
    A_WRITE(0);
    BAR();

    for (int kt2 = 0; kt2 < NT / 2; ++kt2) {
        const int t0 = 2 * kt2;
        // ---- even tile t0 (buf0, set0); stage t0+1 -> buf1 ----
        MAKESZ();               // group kt2 (s/z loaded last odd phase / prologue)
        A_LOAD(t0 + 1);         // issued early; lands during COMPUTE
        LOADB(1);               // B(t0+1) in flight
        COMPUTE(0, 0);
        A_WRITE(1);             // vm-wait hidden behind COMPUTE
        BAR();

        // ---- odd tile t0+1 (buf1, set1); stage t0+2 -> buf0 ----
        if (kt2 + 1 < NT / 2) {
            A_LOAD(t0 + 2);
            LOADB(0);
            LOADSZ(kt2 + 1);    // next group's raw s/z
            COMPUTE(1, 1);      // same group kt2 (GROUP=128 = 2 K-tiles)
            A_WRITE(0);
        } else {
            COMPUTE(1, 1);
        }
        BAR();
    }

#undef A_LOAD
#undef A_WRITE
#undef LOADB
#undef LOADSZ
#undef MAKESZ
#undef COMPUTE

    // epilogue: C/D layout col = lane&15, row = (lane>>4)*4 + reg
    const int ccol0 = n0 + wid * 32 + lr;
    float bj[2];
#pragma unroll
    for (int j = 0; j < 2; ++j) bj[j] = bias[ccol0 + j * 16];
#pragma unroll
    for (int i = 0; i < 8; ++i) {
        const int rbase = m0 + i * 16 + lk * 4;
#pragma unroll
        for (int j = 0; j < 2; ++j) {
            const int col = ccol0 + j * 16;
#pragma unroll
            for (int r = 0; r < 4; ++r)
                out[(size_t)(rbase + r) * N_DIM + col] = acc[i][j][r] + bj[j];
        }
    }
}

extern "C" void kernel_launch(void* const* d_in, const int* in_sizes, int n_in,
                              void* d_out, int out_size, void* d_ws, size_t ws_size,
                              hipStream_t stream) {
    const float*    xp = (const float*)d_in[0];
    const uint32_t* qw = (const uint32_t*)d_in[1];
    const uint32_t* qz = (const uint32_t*)d_in[2];
    const float*    sc = (const float*)d_in[3];
    const float*    bi = (const float*)d_in[4];
    float*          op = (float*)d_out;
    (void)in_sizes; (void)n_in; (void)d_ws; (void)ws_size; (void)out_size;

    qgemm_kernel<<<dim3(NWG), dim3(256), 0, stream>>>(xp, qw, qz, sc, bi, op);
}

// Round 14
// 909.570 us; speedup vs baseline: 5.8977x; 1.0076x over previous
//
#include <hip/hip_runtime.h>
#include <stdint.h>

#define K_DIM 4096
#define N_DIM 11008
#define M_DIM 8192

constexpr int BM = 128, BN = 128, BK = 64;
constexpr int LDA = 64;            // f16 elems/row (128 B, pow2) + XOR slot swizzle
constexpr int NT  = K_DIM / BK;    // 64
constexpr int NZW = N_DIM / 8;     // 1376
constexpr int NXT = N_DIM / BN;    // 86
constexpr int NWG = NXT * (M_DIM / BM);  // 5504 = 8 * 688

typedef _Float16 f16x2 __attribute__((ext_vector_type(2)));
typedef _Float16 f16x8 __attribute__((ext_vector_type(8)));
typedef float    f32x4 __attribute__((ext_vector_type(4)));
union H8 { f16x8 v; f16x2 p[4]; };

// word w holds nibbles for k-offsets 0..7; output k-order (0,4,1,5,2,6,3,7).
// Exact: (1024+q) - (1024+z) is Sterbenz-exact; single rounding on *s.
__device__ __forceinline__ f16x8 dq_word(uint32_t w, f16x2 ss, f16x2 zz) {
    H8 r;
    uint32_t t0 = ( w        & 0x000F000Fu) | 0x64006400u;
    uint32_t t1 = ((w >> 4)  & 0x000F000Fu) | 0x64006400u;
    uint32_t t2 = ((w >> 8)  & 0x000F000Fu) | 0x64006400u;
    uint32_t t3 = ((w >> 12) & 0x000F000Fu) | 0x64006400u;
    r.p[0] = (__builtin_bit_cast(f16x2, t0) - zz) * ss;
    r.p[1] = (__builtin_bit_cast(f16x2, t1) - zz) * ss;
    r.p[2] = (__builtin_bit_cast(f16x2, t2) - zz) * ss;
    r.p[3] = (__builtin_bit_cast(f16x2, t3) - zz) * ss;
    return r.v;
}

// No-drain barrier (R7-proven): lgkmcnt(0) for cross-wave LDS visibility,
// raw s_barrier, sched_barrier fence (rule #18). Global loads stay in flight.
#define BAR() do {                                           \
    asm volatile("s_waitcnt lgkmcnt(0)" ::: "memory");       \
    __builtin_amdgcn_s_barrier();                            \
    __builtin_amdgcn_sched_barrier(0);                       \
} while (0)

// ===== 128x128 tile, 4 waves side-by-side in N; wave-tile 128x32 (R13) =====
// + T2 XOR swizzle: row has 8 16B-slots; physical slot = logical ^ (row&7).
// Write side: slot' = acp ^ (arow&7).  Read side: slot' = (ks*4+lk) ^ (lr&7).
// Same involution both sides (rule #21); <=2 lanes/bank per 16-lane beat.
__global__ __launch_bounds__(256, 3)
void qgemm_kernel(const float* __restrict__ x, const uint32_t* __restrict__ qw,
                  const uint32_t* __restrict__ qz, const float* __restrict__ sc,
                  const float* __restrict__ bias, float* __restrict__ out)
{
    __shared__ _Float16 As[2][BM * LDA];   // 2 x 16 KiB

    const int tid  = threadIdx.x;
    const int lid  = (blockIdx.x & 7) * (NWG / 8) + (blockIdx.x >> 3); // XCD swizzle
    const int m0   = (lid / NXT) * BM;
    const int n0   = (lid % NXT) * BN;

    const int lane = tid & 63, wid = tid >> 6;   // wid 0..3 = N slot
    const int lr = lane & 15, lk = lane >> 4;
    const int sw = lr & 7;                        // read-side swizzle key

    const int arow = tid >> 3;        // A staging row (0..31, +i*32)
    const int acp  = tid & 7;         // A staging col-octet (logical slot)
    const int wslot = acp ^ (arow & 7);           // write-side physical slot

    f32x4 acc[8][2];
#pragma unroll
    for (int i = 0; i < 8; ++i)
#pragma unroll
        for (int j = 0; j < 2; ++j) {
            f32x4 z = {0.f, 0.f, 0.f, 0.f};
            acc[i][j] = z;
        }

    f32x4    aS[4][2];                // single A staging set (32 regs)
    uint32_t breg[2][4];              // [set][ks*2+j]
    f16x2    ssv[2], zzv[2];
    float    s_nxt[2];
    uint32_t z_nxt[2];

    const int ncb = n0 + wid * 32 + lr;   // lane's base col; covers ncb, ncb+16
    const int shz = 4 * (lr & 7);
    const float* xbase = x + (size_t)(m0 + arow) * K_DIM + acp * 8;

    const uint32_t* qp0 = qw + (size_t)lk * N_DIM + ncb;   // ks=0 word row
    const uint32_t* qp1 = qp0 + (size_t)4 * N_DIM;         // ks=1 word row

#define A_LOAD(KT) do { const float* ap_ = xbase + (KT) * BK;                \
    _Pragma("unroll") for (int i = 0; i < 4; ++i) {                          \
        const float* src_ = ap_ + (size_t)(i * 32) * K_DIM;                  \
        aS[i][0] = *(const f32x4*)(src_);                                    \
        aS[i][1] = *(const f32x4*)(src_ + 4); } } while (0)

#define A_WRITE(BUF) do {                                                    \
    _Pragma("unroll") for (int i = 0; i < 4; ++i) { H8 v_;                   \
        _Pragma("unroll") for (int j = 0; j < 4; ++j)                        \
            v_.p[j] = __builtin_bit_cast(f16x2,                              \
                __builtin_amdgcn_cvt_pkrtz(aS[i][0][j], aS[i][1][j]));       \
        *(f16x8*)&As[BUF][(arow + i * 32) * LDA + wslot * 8] = v_.v; } } while (0)

#define LOADB(SET) do {                                                      \
    breg[SET][0] = qp0[0];  breg[SET][1] = qp0[16];                          \
    breg[SET][2] = qp1[0];  breg[SET][3] = qp1[16];                          \
    qp0 += (size_t)8 * N_DIM; qp1 += (size_t)8 * N_DIM; } while (0)

#define LOADSZ(G) do { _Pragma("unroll") for (int j = 0; j < 2; ++j) {       \
    s_nxt[j] = sc[(size_t)(G) * N_DIM + ncb + j * 16];                       \
    z_nxt[j] = qz[(size_t)(G) * NZW + (ncb >> 3) + j * 2]; } } while (0)

#define MAKESZ() do { _Pragma("unroll") for (int j = 0; j < 2; ++j) {        \
    _Float16 zh = (_Float16)(float)(1024u + ((z_nxt[j] >> shz) & 15u));      \
    _Float16 sh = (_Float16)s_nxt[j];                                        \
    f16x2 sp = {sh, sh}; ssv[j] = sp;                                        \
    f16x2 zp = {zh, zh}; zzv[j] = zp; } } while (0)

// wave spans ALL 128 rows (i=0..7), 32 cols (j=0..1); swizzled A-frag reads
#define COMPUTE(BUF, SET) do {                                               \
    _Pragma("unroll") for (int ks = 0; ks < 2; ++ks) {                       \
        f16x8 bf0 = dq_word(breg[SET][ks * 2],     ssv[0], zzv[0]);          \
        f16x8 bf1 = dq_word(breg[SET][ks * 2 + 1], ssv[1], zzv[1]);          \
        const int rs_ = ((ks * 4 + lk) ^ sw) * 8;                            \
        _Pragma("unroll") for (int i = 0; i < 8; ++i) {                      \
            f16x8 af_ = *(const f16x8*)&As[BUF][(i * 16 + lr) * LDA + rs_];  \
            acc[i][0] = __builtin_amdgcn_mfma_f32_16x16x32_f16(af_, bf0, acc[i][0], 0, 0, 0); \
            acc[i][1] = __builtin_amdgcn_mfma_f32_16x16x32_f16(af_, bf1, acc[i][1], 0, 0, 0); \
        } } } while (0)

    // ---------------- prologue: tile 0 -> buf0, B(0) -> set0, group 0 ----------------
    LOADSZ(0);
    A_LOAD(0);
    LOADB(0);
    A_WRITE(0);
    BAR();

    for (int kt2 = 0; kt2 < NT / 2; ++kt2) {
        const int t0 = 2 * kt2;
        // ---- even tile t0 (buf0, set0); stage t0+1 -> buf1 ----
        MAKESZ();               // group kt2 (s/z loaded last odd phase / prologue)
        A_LOAD(t0 + 1);         // issued early; lands during COMPUTE
        LOADB(1);               // B(t0+1) in flight
        COMPUTE(0, 0);
        A_WRITE(1);             // vm-wait hidden behind COMPUTE
        BAR();

        // ---- odd tile t0+1 (buf1, set1); stage t0+2 -> buf0 ----
        if (kt2 + 1 < NT / 2) {
            A_LOAD(t0 + 2);
            LOADB(0);
            LOADSZ(kt2 + 1);    // next group's raw s/z
            COMPUTE(1, 1);      // same group kt2 (GROUP=128 = 2 K-tiles)
            A_WRITE(0);
        } else {
            COMPUTE(1, 1);
        }
        BAR();
    }

#undef A_LOAD
#undef A_WRITE
#undef LOADB
#undef LOADSZ
#undef MAKESZ
#undef COMPUTE

    // epilogue: C/D layout col = lane&15, row = (lane>>4)*4 + reg
    const int ccol0 = n0 + wid * 32 + lr;
    float bj[2];
#pragma unroll
    for (int j = 0; j < 2; ++j) bj[j] = bias[ccol0 + j * 16];
#pragma unroll
    for (int i = 0; i < 8; ++i) {
        const int rbase = m0 + i * 16 + lk * 4;
#pragma unroll
        for (int j = 0; j < 2; ++j) {
            const int col = ccol0 + j * 16;
#pragma unroll
            for (int r = 0; r < 4; ++r)
                out[(size_t)(rbase + r) * N_DIM + col] = acc[i][j][r] + bj[j];
        }
    }
}

extern "C" void kernel_launch(void* const* d_in, const int* in_sizes, int n_in,
                              void* d_out, int out_size, void* d_ws, size_t ws_size,
                              hipStream_t stream) {
    const float*    xp = (const float*)d_in[0];
    const uint32_t* qw = (const uint32_t*)d_in[1];
    const uint32_t* qz = (const uint32_t*)d_in[2];
    const float*    sc = (const float*)d_in[3];
    const float*    bi = (const float*)d_in[4];
    float*          op = (float*)d_out;
    (void)in_sizes; (void)n_in; (void)d_ws; (void)ws_size; (void)out_size;

    qgemm_kernel<<<dim3(NWG), dim3(256), 0, stream>>>(xp, qw, qz, sc, bi, op);
}

// Round 15
// 755.990 us; speedup vs baseline: 7.0959x; 1.2032x over previous
//
#include <hip/hip_runtime.h>
#include <stdint.h>

#define K_DIM 4096
#define N_DIM 11008
#define M_DIM 8192

constexpr int BM = 128, BN = 128, BK = 64;
constexpr int NT  = K_DIM / BK;    // 64
constexpr int NZW = N_DIM / 8;     // 1376
constexpr int NXT = N_DIM / BN;    // 86
constexpr int MXT = M_DIM / BM;    // 64
constexpr int NWG = NXT * MXT;     // 5504 = 8 * 688
constexpr int TILE_ELEMS = BM * BK;  // 8192 f16 = 16 KiB per K-tile

typedef _Float16 f16x2 __attribute__((ext_vector_type(2)));
typedef _Float16 f16x8 __attribute__((ext_vector_type(8)));
typedef float    f32x4 __attribute__((ext_vector_type(4)));
union H8 { f16x8 v; f16x2 p[4]; };

// word w holds nibbles for k-offsets 0..7; output k-order (0,4,1,5,2,6,3,7).
// Exact: (1024+q) - (1024+z) is Sterbenz-exact; single rounding on *s.
__device__ __forceinline__ f16x8 dq_word(uint32_t w, f16x2 ss, f16x2 zz) {
    H8 r;
    uint32_t t0 = ( w        & 0x000F000Fu) | 0x64006400u;
    uint32_t t1 = ((w >> 4)  & 0x000F000Fu) | 0x64006400u;
    uint32_t t2 = ((w >> 8)  & 0x000F000Fu) | 0x64006400u;
    uint32_t t3 = ((w >> 12) & 0x000F000Fu) | 0x64006400u;
    r.p[0] = (__builtin_bit_cast(f16x2, t0) - zz) * ss;
    r.p[1] = (__builtin_bit_cast(f16x2, t1) - zz) * ss;
    r.p[2] = (__builtin_bit_cast(f16x2, t2) - zz) * ss;
    r.p[3] = (__builtin_bit_cast(f16x2, t3) - zz) * ss;
    return r.v;
}

// ========= pre-pass: x fp32 -> f16, fragment-major 128-row tiles =========
// x16 layout: [mt(64)][kt(64)][fk(8)][row(128)][octet(8)], octet = pairs
// (e, e+4) of k = kt*64 + fk*8 + e  (matches dq_word's output permutation).
// Layout correctness + 0-conflict reads verified by R9's pass (spill aside).
__global__ __launch_bounds__(256)
void prep_kernel(const float* __restrict__ x, _Float16* __restrict__ x16) {
    const int b  = blockIdx.x;          // mt*64 + kt
    const int mt = b >> 6, kt = b & 63;
    _Float16* dst = x16 + (size_t)b * TILE_ELEMS;
#pragma unroll
    for (int it = 0; it < 4; ++it) {
        const int o   = it * 256 + threadIdx.x;   // 0..1023 = fk*128 + row
        const int fk  = o >> 7, row = o & 127;
        const float* src = x + (size_t)(mt * 128 + row) * K_DIM + kt * 64 + fk * 8;
        f32x4 a0 = *(const f32x4*)src;
        f32x4 a1 = *(const f32x4*)(src + 4);
        H8 v;
#pragma unroll
        for (int j = 0; j < 4; ++j)
            v.p[j] = __builtin_bit_cast(f16x2, __builtin_amdgcn_cvt_pkrtz(a0[j], a1[j]));
        *(f16x8*)(dst + (size_t)o * 8) = v.v;
    }
}

// ===== 128x128 tile, 4 waves in N (wave-tile 128x32, acc=64, R14-safe),
// ===== A via global_load_lds DMA dbuf: no in-loop ds_write/cvt/staging regs.
__global__ __launch_bounds__(256, 4)
void qgemm_dma_kernel(const _Float16* __restrict__ x16, const uint32_t* __restrict__ qw,
                      const uint32_t* __restrict__ qz, const float* __restrict__ sc,
                      const float* __restrict__ bias, float* __restrict__ out)
{
    __shared__ _Float16 As[2 * TILE_ELEMS];   // 2 x 16 KiB, fragment-major, linear

    const int tid  = threadIdx.x;
    const int lid  = (blockIdx.x & 7) * (NWG / 8) + (blockIdx.x >> 3); // XCD swizzle
    const int mt   = lid / NXT;
    const int n0   = (lid % NXT) * BN;

    const int lane = tid & 63, wid = tid >> 6;   // wid 0..3 = N slot
    const int lr = lane & 15, lk = lane >> 4;

    f32x4 acc[8][2];
#pragma unroll
    for (int i = 0; i < 8; ++i)
#pragma unroll
        for (int j = 0; j < 2; ++j) {
            f32x4 z = {0.f, 0.f, 0.f, 0.f};
            acc[i][j] = z;
        }

    uint32_t breg[2][4];              // [set][ks*2+j]
    f16x2    ssv[2], zzv[2];
    float    s_nxt[2];
    uint32_t z_nxt[2];

    const int ncb = n0 + wid * 32 + lr;   // lane's base col; covers ncb, ncb+16
    const int shz = 4 * (lr & 7);

    const _Float16* xsrc = x16 + (size_t)mt * (64 * TILE_ELEMS) + tid * 8;
    const uint32_t* qp0 = qw + (size_t)lk * N_DIM + ncb;   // ks=0 word row
    const uint32_t* qp1 = qp0 + (size_t)4 * N_DIM;         // ks=1 word row

// 256 threads x 4 DMAs x 16 B = 16 KiB tile (linear dst, per intrinsic contract)
#define STAGE(BUF, KT) do {                                                  \
    const _Float16* s_ = xsrc + (size_t)(KT) * TILE_ELEMS;                   \
    _Float16* d_ = &As[(BUF) * TILE_ELEMS + tid * 8];                        \
    _Pragma("unroll") for (int it = 0; it < 4; ++it)                         \
        __builtin_amdgcn_global_load_lds(                                    \
            (const __attribute__((address_space(1))) void*)(s_ + it * 2048), \
            (__attribute__((address_space(3))) void*)(d_ + it * 2048), 16, 0, 0); \
    } while (0)

#define LOADB(SET) do {                                                      \
    breg[SET][0] = qp0[0];  breg[SET][1] = qp0[16];                          \
    breg[SET][2] = qp1[0];  breg[SET][3] = qp1[16];                          \
    qp0 += (size_t)8 * N_DIM; qp1 += (size_t)8 * N_DIM; } while (0)

#define LOADSZ(G) do { _Pragma("unroll") for (int j = 0; j < 2; ++j) {       \
    s_nxt[j] = sc[(size_t)(G) * N_DIM + ncb + j * 16];                       \
    z_nxt[j] = qz[(size_t)(G) * NZW + (ncb >> 3) + j * 2]; } } while (0)

#define MAKESZ() do { _Pragma("unroll") for (int j = 0; j < 2; ++j) {        \
    _Float16 zh = (_Float16)(float)(1024u + ((z_nxt[j] >> shz) & 15u));      \
    _Float16 sh = (_Float16)s_nxt[j];                                        \
    f16x2 sp = {sh, sh}; ssv[j] = sp;                                        \
    f16x2 zp = {zh, zh}; zzv[j] = zp; } } while (0)

// wave spans ALL 128 rows (i=0..7), 32 cols (j=0..1). Fragment-major reads:
// 16-lane beat = 256 B contiguous -> conflict-free (R9: SQ_LDS_BANK_CONFLICT=0).
#define COMPUTE(BUF, SET) do {                                               \
    _Pragma("unroll") for (int ks = 0; ks < 2; ++ks) {                       \
        f16x8 bf0 = dq_word(breg[SET][ks * 2],     ssv[0], zzv[0]);          \
        f16x8 bf1 = dq_word(breg[SET][ks * 2 + 1], ssv[1], zzv[1]);          \
        const int fo_ = (BUF) * TILE_ELEMS + (ks * 4 + lk) * 1024 + lr * 8;  \
        _Pragma("unroll") for (int i = 0; i < 8; ++i) {                      \
            f16x8 af_ = *(const f16x8*)&As[fo_ + i * 128];                   \
            acc[i][0] = __builtin_amdgcn_mfma_f32_16x16x32_f16(af_, bf0, acc[i][0], 0, 0, 0); \
            acc[i][1] = __builtin_amdgcn_mfma_f32_16x16x32_f16(af_, bf1, acc[i][1], 0, 0, 0); \
        } } } while (0)

    // ---------------- prologue: tile 0 -> buf0 via DMA, B(0), group 0 ----------------
    LOADSZ(0);
    STAGE(0, 0);
    LOADB(0);
    MAKESZ();
    __syncthreads();    // vmcnt(0) drain: tile-0 DMA complete

    for (int kt2 = 0; kt2 < NT / 2; ++kt2) {
        const int t0 = 2 * kt2;
        // ---- even tile t0 (buf0, set0); DMA t0+1 -> buf1 ----
        STAGE(1, t0 + 1);       // DMA issued; lands during COMPUTE
        LOADB(1);               // B(t0+1) in flight
        COMPUTE(0, 0);
        __syncthreads();        // drain cheap: DMAs issued a full COMPUTE ago

        // ---- odd tile t0+1 (buf1, set1); DMA t0+2 -> buf0 ----
        if (kt2 + 1 < NT / 2) {
            STAGE(0, t0 + 2);
            LOADB(0);
            LOADSZ(kt2 + 1);    // next group's raw s/z
            COMPUTE(1, 1);      // same group kt2 (GROUP=128 = 2 K-tiles)
            MAKESZ();           // group kt2+1 (after COMPUTE consumed old ssv/zzv)
        } else {
            COMPUTE(1, 1);
        }
        __syncthreads();
    }

#undef STAGE
#undef LOADB
#undef LOADSZ
#undef MAKESZ
#undef COMPUTE

    // epilogue: C/D layout col = lane&15, row = (lane>>4)*4 + reg
    const int ccol0 = n0 + wid * 32 + lr;
    float bj[2];
#pragma unroll
    for (int j = 0; j < 2; ++j) bj[j] = bias[ccol0 + j * 16];
    const int m0 = mt * BM;
#pragma unroll
    for (int i = 0; i < 8; ++i) {
        const int rbase = m0 + i * 16 + lk * 4;
#pragma unroll
        for (int j = 0; j < 2; ++j) {
            const int col = ccol0 + j * 16;
#pragma unroll
            for (int r = 0; r < 4; ++r)
                out[(size_t)(rbase + r) * N_DIM + col] = acc[i][j][r] + bj[j];
        }
    }
}

// ================= fallback (R14 kernel, 910 µs proven) for small ws =================
constexpr int FB_LDA = 64;

#define BAR() do {                                           \
    asm volatile("s_waitcnt lgkmcnt(0)" ::: "memory");       \
    __builtin_amdgcn_s_barrier();                            \
    __builtin_amdgcn_sched_barrier(0);                       \
} while (0)

__global__ __launch_bounds__(256, 3)
void qgemm_fb_kernel(const float* __restrict__ x, const uint32_t* __restrict__ qw,
                     const uint32_t* __restrict__ qz, const float* __restrict__ sc,
                     const float* __restrict__ bias, float* __restrict__ out)
{
    __shared__ _Float16 As[2][BM * FB_LDA];

    const int tid  = threadIdx.x;
    const int lid  = (blockIdx.x & 7) * (NWG / 8) + (blockIdx.x >> 3);
    const int m0   = (lid / NXT) * BM;
    const int n0   = (lid % NXT) * BN;

    const int lane = tid & 63, wid = tid >> 6;
    const int lr = lane & 15, lk = lane >> 4;
    const int sw = lr & 7;

    const int arow = tid >> 3;
    const int acp  = tid & 7;
    const int wslot = acp ^ (arow & 7);

    f32x4 acc[8][2];
#pragma unroll
    for (int i = 0; i < 8; ++i)
#pragma unroll
        for (int j = 0; j < 2; ++j) { f32x4 z = {0.f,0.f,0.f,0.f}; acc[i][j] = z; }

    f32x4    aS[4][2];
    uint32_t breg[2][4];
    f16x2    ssv[2], zzv[2];
    float    s_nxt[2];
    uint32_t z_nxt[2];

    const int ncb = n0 + wid * 32 + lr;
    const int shz = 4 * (lr & 7);
    const float* xbase = x + (size_t)(m0 + arow) * K_DIM + acp * 8;

    const uint32_t* qp0 = qw + (size_t)lk * N_DIM + ncb;
    const uint32_t* qp1 = qp0 + (size_t)4 * N_DIM;

#define A_LOAD(KT) do { const float* ap_ = xbase + (KT) * BK;                \
    _Pragma("unroll") for (int i = 0; i < 4; ++i) {                          \
        const float* src_ = ap_ + (size_t)(i * 32) * K_DIM;                  \
        aS[i][0] = *(const f32x4*)(src_);                                    \
        aS[i][1] = *(const f32x4*)(src_ + 4); } } while (0)

#define A_WRITE(BUF) do {                                                    \
    _Pragma("unroll") for (int i = 0; i < 4; ++i) { H8 v_;                   \
        _Pragma("unroll") for (int j = 0; j < 4; ++j)                        \
            v_.p[j] = __builtin_bit_cast(f16x2,                              \
                __builtin_amdgcn_cvt_pkrtz(aS[i][0][j], aS[i][1][j]));       \
        *(f16x8*)&As[BUF][(arow + i * 32) * FB_LDA + wslot * 8] = v_.v; } } while (0)

#define LOADB(SET) do {                                                      \
    breg[SET][0] = qp0[0];  breg[SET][1] = qp0[16];                          \
    breg[SET][2] = qp1[0];  breg[SET][3] = qp1[16];                          \
    qp0 += (size_t)8 * N_DIM; qp1 += (size_t)8 * N_DIM; } while (0)

#define LOADSZ(G) do { _Pragma("unroll") for (int j = 0; j < 2; ++j) {       \
    s_nxt[j] = sc[(size_t)(G) * N_DIM + ncb + j * 16];                       \
    z_nxt[j] = qz[(size_t)(G) * NZW + (ncb >> 3) + j * 2]; } } while (0)

#define MAKESZ() do { _Pragma("unroll") for (int j = 0; j < 2; ++j) {        \
    _Float16 zh = (_Float16)(float)(1024u + ((z_nxt[j] >> shz) & 15u));      \
    _Float16 sh = (_Float16)s_nxt[j];                                        \
    f16x2 sp = {sh, sh}; ssv[j] = sp;                                        \
    f16x2 zp = {zh, zh}; zzv[j] = zp; } } while (0)

#define COMPUTE(BUF, SET) do {                                               \
    _Pragma("unroll") for (int ks = 0; ks < 2; ++ks) {                       \
        f16x8 bf0 = dq_word(breg[SET][ks * 2],     ssv[0], zzv[0]);          \
        f16x8 bf1 = dq_word(breg[SET][ks * 2 + 1], ssv[1], zzv[1]);          \
        const int rs_ = ((ks * 4 + lk) ^ sw) * 8;                            \
        _Pragma("unroll") for (int i = 0; i < 8; ++i) {                      \
            f16x8 af_ = *(const f16x8*)&As[BUF][(i * 16 + lr) * FB_LDA + rs_]; \
            acc[i][0] = __builtin_amdgcn_mfma_f32_16x16x32_f16(af_, bf0, acc[i][0], 0, 0, 0); \
            acc[i][1] = __builtin_amdgcn_mfma_f32_16x16x32_f16(af_, bf1, acc[i][1], 0, 0, 0); \
        } } } while (0)

    LOADSZ(0);
    A_LOAD(0);
    LOADB(0);
    A_WRITE(0);
    BAR();

    for (int kt2 = 0; kt2 < NT / 2; ++kt2) {
        const int t0 = 2 * kt2;
        MAKESZ();
        A_LOAD(t0 + 1);
        LOADB(1);
        COMPUTE(0, 0);
        A_WRITE(1);
        BAR();

        if (kt2 + 1 < NT / 2) {
            A_LOAD(t0 + 2);
            LOADB(0);
            LOADSZ(kt2 + 1);
            COMPUTE(1, 1);
            A_WRITE(0);
        } else {
            COMPUTE(1, 1);
        }
        BAR();
    }

#undef A_LOAD
#undef A_WRITE
#undef LOADB
#undef LOADSZ
#undef MAKESZ
#undef COMPUTE

    const int ccol0 = n0 + wid * 32 + lr;
    float bj[2];
#pragma unroll
    for (int j = 0; j < 2; ++j) bj[j] = bias[ccol0 + j * 16];
#pragma unroll
    for (int i = 0; i < 8; ++i) {
        const int rbase = m0 + i * 16 + lk * 4;
#pragma unroll
        for (int j = 0; j < 2; ++j) {
            const int col = ccol0 + j * 16;
#pragma unroll
            for (int r = 0; r < 4; ++r)
                out[(size_t)(rbase + r) * N_DIM + col] = acc[i][j][r] + bj[j];
        }
    }
}

extern "C" void kernel_launch(void* const* d_in, const int* in_sizes, int n_in,
                              void* d_out, int out_size, void* d_ws, size_t ws_size,
                              hipStream_t stream) {
    const float*    xp = (const float*)d_in[0];
    const uint32_t* qw = (const uint32_t*)d_in[1];
    const uint32_t* qz = (const uint32_t*)d_in[2];
    const float*    sc = (const float*)d_in[3];
    const float*    bi = (const float*)d_in[4];
    float*          op = (float*)d_out;
    (void)in_sizes; (void)n_in; (void)out_size;

    const size_t need = (size_t)M_DIM * K_DIM * sizeof(_Float16); // 64 MiB
    if (ws_size >= need) {
        prep_kernel<<<dim3(MXT * NT), dim3(256), 0, stream>>>(xp, (_Float16*)d_ws);
        qgemm_dma_kernel<<<dim3(NWG), dim3(256), 0, stream>>>((const _Float16*)d_ws, qw, qz, sc, bi, op);
    } else {
        qgemm_fb_kernel<<<dim3(NWG), dim3(256), 0, stream>>>(xp, qw, qz, sc, bi, op);
    }
}